// Round 6
// baseline (7002.164 us; speedup 1.0000x reference)
//
#include <hip/hip_runtime.h>
#include <math.h>

typedef long long i64;
#define NN_ 65536L

typedef __attribute__((ext_vector_type(8))) short bf16x8;
typedef __attribute__((ext_vector_type(4))) float f32x4;

__device__ inline unsigned short f2bf(float f){
  unsigned int u = __float_as_uint(f);
  return (unsigned short)((u + 0x7FFFu + ((u>>16)&1u)) >> 16);
}

// ---------------- elementwise ----------------
__global__ __launch_bounds__(256) void copy_k(float* __restrict__ d, const float* __restrict__ s, long n){
  long i = (long)blockIdx.x*blockDim.x + threadIdx.x;
  if (i < n) d[i] = s[i];
}

__global__ __launch_bounds__(256) void muladd_k(float* __restrict__ d, const float* __restrict__ a,
                                                const float* __restrict__ b, long n){
  long i = (long)blockIdx.x*blockDim.x + threadIdx.x;
  if (i < n) d[i] += a[i]*b[i];
}

// out[j,i,:] = in[i,j,:]   (pair transpose, c contiguous both sides)
__global__ __launch_bounds__(128) void transpose_pair_k(float* __restrict__ out, const float* __restrict__ in){
  int blk = blockIdx.x; int i = blk >> 8, j = blk & 255; int c = threadIdx.x;
  out[((i64)(j*256+i))*128 + c] = in[((i64)blk)*128 + c];
}

// pa += src (optionally with (i,j)->(j,i) transpose of the block index)
__global__ __launch_bounds__(128) void resadd_k(float* __restrict__ pa, const float* __restrict__ src, int T){
  int blk = blockIdx.x; int c = threadIdx.x;
  float v = src[((i64)blk)*128 + c];
  i64 didx;
  if (T){ int i = blk>>8, j = blk&255; didx = ((i64)(j*256+i))*128 + c; }
  else didx = ((i64)blk)*128 + c;
  pa[didx] += v;
}

// channel-major [128][65536] -> row-major [65536][128]
__global__ __launch_bounds__(256) void chw2hwc_k(const float* __restrict__ in, float* __restrict__ out){
  __shared__ float t[32][33];
  int r0 = blockIdx.x*32, c0 = blockIdx.y*32;
  int tx = threadIdx.x & 31, ty = threadIdx.x >> 5;
  for (int i = ty; i < 32; i += 8) t[i][tx] = in[(i64)(c0+i)*NN_ + r0 + tx];
  __syncthreads();
  for (int i = ty; i < 32; i += 8) out[(i64)(r0+i)*128 + c0 + tx] = t[tx][i];
}

// row-major [65536][128] -> ch-major [128][65536] with per-row mask
__global__ __launch_bounds__(256) void tr_mask_k(const float* __restrict__ in, const float* __restrict__ mask,
                                                 float* __restrict__ out){
  __shared__ float t[32][33];
  int r0 = blockIdx.x*32, c0 = blockIdx.y*32;
  int tx = threadIdx.x & 31, ty = threadIdx.x >> 5;
  for (int i = ty; i < 32; i += 8) t[i][tx] = in[(i64)(r0+i)*128 + c0 + tx];
  __syncthreads();
  for (int i = ty; i < 32; i += 8) out[(i64)(c0+i)*NN_ + r0 + tx] = t[tx][i] * mask[r0+tx];
}

// nb [q,k,h=4] -> nbT [h][k][q]
__global__ __launch_bounds__(256) void nbT_k(const float* __restrict__ in, float* __restrict__ out){
  int kk = blockIdx.x, qq = threadIdx.x;
  float4 vv = *(const float4*)(in + ((i64)qq*256 + kk)*4);
  out[0*65536 + kk*256 + qq] = vv.x;
  out[1*65536 + kk*256 + qq] = vv.y;
  out[2*65536 + kk*256 + qq] = vv.z;
  out[3*65536 + kk*256 + qq] = vv.w;
}

// ---------------- LayerNorm (rowwise) ----------------
__global__ __launch_bounds__(128) void ln_k(const float* __restrict__ in, float* __restrict__ out,
                                            const float* __restrict__ w, int C){
  i64 row = blockIdx.x;
  const float* x = in + row*C;
  float* y = out + row*C;
  int tid = threadIdx.x;
  float s=0.f, s2=0.f;
  for (int c=tid;c<C;c+=128){ float v = x[c]; s += v; s2 += v*v; }
  __shared__ float rs[128], rq[128];
  rs[tid]=s; rq[tid]=s2; __syncthreads();
  for (int off=64;off>0;off>>=1){ if (tid<off){ rs[tid]+=rs[tid+off]; rq[tid]+=rq[tid+off]; } __syncthreads(); }
  float mu = rs[0]/C;
  float var = rq[0]/C - mu*mu;
  float inv = rsqrtf(var + 1e-5f);
  for (int c=tid;c<C;c+=128) y[c] = (x[c]-mu)*inv*w[c] + w[C+c];
}

// ---------------- bf16 MFMA GEMM: 128x128 tile, 256 thr (2x2 waves of 64x64) ----------------
// Requires M%128==0, N%128==0, K%32==0. A,B fp32 in global; converted to bf16 during staging.
template<bool TA, bool TB>
__global__ __launch_bounds__(256) void mgemm_k(
    const float* __restrict__ A, int lda, i64 sA,
    const float* __restrict__ B, int ldb, i64 sB,
    float* __restrict__ C, int ldc, i64 sC,
    int M, int N, int K,
    const float* __restrict__ bias, float scale, int act,
    const float* __restrict__ rowmul, int combine)
{
  A += (i64)blockIdx.z * sA;
  B += (i64)blockIdx.z * sB;
  C += (i64)blockIdx.z * sC;
  int m0 = blockIdx.x * 128, n0 = blockIdx.y * 128;
  int tid = threadIdx.x;
  int wave = tid >> 6, lane = tid & 63;
  int quad = lane >> 4, mr = lane & 15;
  int wm = (wave >> 1) * 64, wn = (wave & 1) * 64;
  __shared__ unsigned short As[128][40];
  __shared__ unsigned short Bs[128][40];
  f32x4 acc[4][4];
  #pragma unroll
  for (int i=0;i<4;i++)
    #pragma unroll
    for (int j=0;j<4;j++) acc[i][j] = (f32x4){0.f,0.f,0.f,0.f};

  for (int k0 = 0; k0 < K; k0 += 32){
    if (!TA){
      #pragma unroll
      for (int it=0; it<4; it++){
        int lin = tid + it*256;
        int r = lin >> 3, c4 = (lin & 7) * 4;
        float4 g = *(const float4*)&A[(i64)(m0+r)*lda + k0 + c4];
        As[r][c4]   = f2bf(g.x); As[r][c4+1] = f2bf(g.y);
        As[r][c4+2] = f2bf(g.z); As[r][c4+3] = f2bf(g.w);
      }
    } else {
      #pragma unroll
      for (int it=0; it<4; it++){
        int lin = tid + it*256;
        int m = lin & 127, kg = (lin >> 7) * 4;
        float v0 = A[(i64)(k0+kg  )*lda + m0 + m];
        float v1 = A[(i64)(k0+kg+1)*lda + m0 + m];
        float v2 = A[(i64)(k0+kg+2)*lda + m0 + m];
        float v3 = A[(i64)(k0+kg+3)*lda + m0 + m];
        As[m][kg] = f2bf(v0); As[m][kg+1] = f2bf(v1);
        As[m][kg+2] = f2bf(v2); As[m][kg+3] = f2bf(v3);
      }
    }
    if (!TB){
      #pragma unroll
      for (int it=0; it<4; it++){
        int lin = tid + it*256;
        int n = lin & 127, kg = (lin >> 7) * 4;
        float v0 = B[(i64)(k0+kg  )*ldb + n0 + n];
        float v1 = B[(i64)(k0+kg+1)*ldb + n0 + n];
        float v2 = B[(i64)(k0+kg+2)*ldb + n0 + n];
        float v3 = B[(i64)(k0+kg+3)*ldb + n0 + n];
        Bs[n][kg] = f2bf(v0); Bs[n][kg+1] = f2bf(v1);
        Bs[n][kg+2] = f2bf(v2); Bs[n][kg+3] = f2bf(v3);
      }
    } else {
      #pragma unroll
      for (int it=0; it<4; it++){
        int lin = tid + it*256;
        int r = lin >> 3, c4 = (lin & 7) * 4;
        float4 g = *(const float4*)&B[(i64)(n0+r)*ldb + k0 + c4];
        Bs[r][c4]   = f2bf(g.x); Bs[r][c4+1] = f2bf(g.y);
        Bs[r][c4+2] = f2bf(g.z); Bs[r][c4+3] = f2bf(g.w);
      }
    }
    __syncthreads();
    bf16x8 af[4], bfr[4];
    #pragma unroll
    for (int i=0;i<4;i++) af[i]  = *(const bf16x8*)&As[wm + i*16 + mr][quad*8];
    #pragma unroll
    for (int j=0;j<4;j++) bfr[j] = *(const bf16x8*)&Bs[wn + j*16 + mr][quad*8];
    #pragma unroll
    for (int i=0;i<4;i++)
      #pragma unroll
      for (int j=0;j<4;j++)
        acc[i][j] = __builtin_amdgcn_mfma_f32_16x16x32_bf16(af[i], bfr[j], acc[i][j], 0, 0, 0);
    __syncthreads();
  }
  #pragma unroll
  for (int i=0;i<4;i++){
    #pragma unroll
    for (int r=0;r<4;r++){
      int m = m0 + wm + i*16 + quad*4 + r;
      float rm = rowmul ? rowmul[m] : 1.f;
      #pragma unroll
      for (int j=0;j<4;j++){
        int n = n0 + wn + j*16 + mr;
        float v = acc[i][j][r] * scale;
        if (bias) v += bias[n];
        if (act == 1) v = fmaxf(v, 0.f);
        else if (act == 2) v = 1.f/(1.f + __expf(-v));
        v *= rm;
        i64 idx = (i64)m*ldc + n;
        if (combine == 0) C[idx] = v;
        else if (combine == 1) C[idx] += v;
        else C[idx] *= v;
      }
    }
  }
}

// ---------------- fused dual-MFMA lin*sigmoid(gate) for tri-mult (M=65536, N=128, K=128) ----------------
// Out[m][n] = (X@Wl+bl)[m][n] * sigmoid((X@Wg+bg)[m][n])   (row-major out; mask applied by tr_mask_k)
__global__ __launch_bounds__(256) void mlrgate_k(
    const float* __restrict__ X,
    const float* __restrict__ Wl, const float* __restrict__ bl,
    const float* __restrict__ Wg, const float* __restrict__ bg,
    float* __restrict__ Out)
{
  int m0 = blockIdx.x * 128;
  int tid = threadIdx.x;
  int wave = tid >> 6, lane = tid & 63;
  int quad = lane >> 4, mr = lane & 15;
  int wm = (wave >> 1) * 64, wn = (wave & 1) * 64;
  __shared__ unsigned short As[128][40], B1s[128][40], B2s[128][40];
  f32x4 acc1[4][4], acc2[4][4];
  #pragma unroll
  for (int i=0;i<4;i++)
    #pragma unroll
    for (int j=0;j<4;j++){ acc1[i][j] = (f32x4){0,0,0,0}; acc2[i][j] = (f32x4){0,0,0,0}; }

  for (int k0 = 0; k0 < 128; k0 += 32){
    #pragma unroll
    for (int it=0; it<4; it++){
      int lin = tid + it*256;
      int r = lin >> 3, c4 = (lin & 7) * 4;
      float4 g = *(const float4*)&X[(i64)(m0+r)*128 + k0 + c4];
      As[r][c4]   = f2bf(g.x); As[r][c4+1] = f2bf(g.y);
      As[r][c4+2] = f2bf(g.z); As[r][c4+3] = f2bf(g.w);
    }
    #pragma unroll
    for (int it=0; it<4; it++){
      int lin = tid + it*256;
      int n = lin & 127, kg = (lin >> 7) * 4;
      float a0 = Wl[(i64)(k0+kg  )*128 + n];
      float a1 = Wl[(i64)(k0+kg+1)*128 + n];
      float a2 = Wl[(i64)(k0+kg+2)*128 + n];
      float a3 = Wl[(i64)(k0+kg+3)*128 + n];
      B1s[n][kg] = f2bf(a0); B1s[n][kg+1] = f2bf(a1);
      B1s[n][kg+2] = f2bf(a2); B1s[n][kg+3] = f2bf(a3);
      float g0 = Wg[(i64)(k0+kg  )*128 + n];
      float g1 = Wg[(i64)(k0+kg+1)*128 + n];
      float g2 = Wg[(i64)(k0+kg+2)*128 + n];
      float g3 = Wg[(i64)(k0+kg+3)*128 + n];
      B2s[n][kg] = f2bf(g0); B2s[n][kg+1] = f2bf(g1);
      B2s[n][kg+2] = f2bf(g2); B2s[n][kg+3] = f2bf(g3);
    }
    __syncthreads();
    bf16x8 af[4], b1f[4], b2f[4];
    #pragma unroll
    for (int i=0;i<4;i++) af[i]  = *(const bf16x8*)&As[wm + i*16 + mr][quad*8];
    #pragma unroll
    for (int j=0;j<4;j++){
      b1f[j] = *(const bf16x8*)&B1s[wn + j*16 + mr][quad*8];
      b2f[j] = *(const bf16x8*)&B2s[wn + j*16 + mr][quad*8];
    }
    #pragma unroll
    for (int i=0;i<4;i++)
      #pragma unroll
      for (int j=0;j<4;j++){
        acc1[i][j] = __builtin_amdgcn_mfma_f32_16x16x32_bf16(af[i], b1f[j], acc1[i][j], 0, 0, 0);
        acc2[i][j] = __builtin_amdgcn_mfma_f32_16x16x32_bf16(af[i], b2f[j], acc2[i][j], 0, 0, 0);
      }
    __syncthreads();
  }
  #pragma unroll
  for (int i=0;i<4;i++){
    #pragma unroll
    for (int r=0;r<4;r++){
      int m = m0 + wm + i*16 + quad*4 + r;
      #pragma unroll
      for (int j=0;j<4;j++){
        int n = wn + j*16 + mr;
        float lv = acc1[i][j][r] + bl[n];
        float gv = acc2[i][j][r] + bg[n];
        Out[(i64)m*128 + n] = lv * (1.f/(1.f + __expf(-gv)));
      }
    }
  }
}

// ---------------- generic batched GEMM (fp32, 64x64 tile) ----------------
template<bool TA, bool TB>
__global__ __launch_bounds__(256) void gemm_k(
    const float* __restrict__ A, int lda, i64 sA,
    const float* __restrict__ B, int ldb, i64 sB,
    float* __restrict__ C, int ldc, i64 sC,
    int M, int N, int K,
    const float* __restrict__ bias, float scale, int act,
    const float* __restrict__ rowmul, int combine)
{
  A += (i64)blockIdx.z * sA;
  B += (i64)blockIdx.z * sB;
  C += (i64)blockIdx.z * sC;
  int m0 = blockIdx.x * 64, n0 = blockIdx.y * 64;
  int tid = threadIdx.x, tx = tid & 15, ty = tid >> 4;
  __shared__ float As[16][68], Bs[16][68];
  float acc[4][4] = {};
  for (int k0 = 0; k0 < K; k0 += 16){
    if (TA){
      for (int l = tid; l < 1024; l += 256){
        int kk = l >> 6, mi = l & 63; int m = m0 + mi;
        As[kk][mi] = (m < M) ? A[(i64)(k0+kk)*lda + m] : 0.f;
      }
    } else {
      for (int l = tid; l < 1024; l += 256){
        int mi = l >> 4, kk = l & 15; int m = m0 + mi;
        As[kk][mi] = (m < M) ? A[(i64)m*lda + k0 + kk] : 0.f;
      }
    }
    if (TB){
      for (int l = tid; l < 1024; l += 256){
        int ni = l >> 4, kk = l & 15; int n = n0 + ni;
        Bs[kk][ni] = (n < N) ? B[(i64)n*ldb + k0 + kk] : 0.f;
      }
    } else {
      for (int l = tid; l < 1024; l += 256){
        int kk = l >> 6, ni = l & 63; int n = n0 + ni;
        Bs[kk][ni] = (n < N) ? B[(i64)(k0+kk)*ldb + n] : 0.f;
      }
    }
    __syncthreads();
    #pragma unroll
    for (int kk = 0; kk < 16; ++kk){
      float4 av4 = *(const float4*)&As[kk][ty*4];
      float4 bv4 = *(const float4*)&Bs[kk][tx*4];
      float av[4] = {av4.x, av4.y, av4.z, av4.w};
      float bv[4] = {bv4.x, bv4.y, bv4.z, bv4.w};
      #pragma unroll
      for (int i=0;i<4;i++)
        #pragma unroll
        for (int j=0;j<4;j++) acc[i][j] = fmaf(av[i], bv[j], acc[i][j]);
    }
    __syncthreads();
  }
  #pragma unroll
  for (int i=0;i<4;i++){
    int m = m0 + ty*4 + i;
    if (m >= M) continue;
    float rm = rowmul ? rowmul[m] : 1.f;
    #pragma unroll
    for (int j=0;j<4;j++){
      int n = n0 + tx*4 + j;
      if (n >= N) continue;
      float v = acc[i][j] * scale;
      if (bias) v += bias[n];
      if (act == 1) v = fmaxf(v, 0.f);
      else if (act == 2) v = 1.f/(1.f + expf(-v));
      v *= rm;
      i64 idx = (i64)m*ldc + n;
      if (combine == 0) C[idx] = v;
      else if (combine == 1) C[idx] += v;
      else C[idx] *= v;
    }
  }
}

// ---------------- thin GEMM (small M): split-K two-phase ----------------
__global__ __launch_bounds__(256) void gemm_part_k(
    const float* __restrict__ A, int lda,
    const float* __restrict__ B, int ldb,
    float* __restrict__ Cp, int M, int N, int K, int chunk)
{
  int m0 = blockIdx.x*16, n0 = blockIdx.y*64, z = blockIdx.z;
  int kb = z*chunk, ke = min(K, kb+chunk);
  int tid = threadIdx.x;
  int mi = tid >> 4, ni4 = (tid & 15)*4;
  __shared__ float As[16][17], Bs[16][68];
  float acc[4] = {0.f,0.f,0.f,0.f};
  for (int k0 = kb; k0 < ke; k0 += 16){
    { int r = tid>>4, c = tid&15; int m = m0+r;
      As[c][r] = (m < M) ? A[(i64)m*lda + k0 + c] : 0.f; }
    for (int l = tid; l < 1024; l += 256){
      int kk = l>>6, nn = l&63; int n = n0+nn;
      Bs[kk][nn] = (n < N) ? B[(i64)(k0+kk)*ldb + n] : 0.f;
    }
    __syncthreads();
    #pragma unroll
    for (int kk=0;kk<16;kk++){
      float a = As[kk][mi];
      float4 b = *(const float4*)&Bs[kk][ni4];
      acc[0]=fmaf(a,b.x,acc[0]); acc[1]=fmaf(a,b.y,acc[1]);
      acc[2]=fmaf(a,b.z,acc[2]); acc[3]=fmaf(a,b.w,acc[3]);
    }
    __syncthreads();
  }
  int m = m0+mi, n = n0+ni4;
  if (m < M && n < N) *(float4*)&Cp[((i64)z*M + m)*N + n] = *(float4*)acc;
}

__global__ __launch_bounds__(256) void gemm_reduce_k(
    const float* __restrict__ Cp, float* __restrict__ C, int ldc,
    int M, int N, int S,
    const float* __restrict__ bias, float scale, int act,
    const float* __restrict__ rowmul, int combine)
{
  i64 idx = (i64)blockIdx.x*256 + threadIdx.x;
  if (idx >= (i64)M*N) return;
  int m = (int)(idx / N), n = (int)(idx % N);
  float s = 0.f;
  for (int z=0; z<S; z++) s += Cp[(i64)z*M*N + idx];
  float v = s*scale;
  if (bias) v += bias[n];
  if (act == 1) v = fmaxf(v, 0.f);
  else if (act == 2) v = 1.f/(1.f + expf(-v));
  if (rowmul) v *= rowmul[m];
  i64 o = (i64)m*ldc + n;
  if (combine == 0) C[o] = v;
  else if (combine == 1) C[o] += v;
  else C[o] *= v;
}

// ---------------- OPM ----------------
__global__ __launch_bounds__(128) void opm_wd_k(const float* __restrict__ right, const float* __restrict__ W,
                                                float* __restrict__ Wd){
  int d = blockIdx.x, c = blockIdx.y, f = threadIdx.x;
  float acc = 0.f;
  #pragma unroll
  for (int e=0;e<32;e++) acc = fmaf(right[d*32+e], W[((i64)c*32+e)*128 + f], acc);
  Wd[((i64)d*32+c)*128 + f] = acc;
}

__global__ __launch_bounds__(128) void opm_final_k(const float* __restrict__ left, const float* __restrict__ Wd,
                                                   const float* __restrict__ ob, const float* __restrict__ sm,
                                                   float* __restrict__ pa){
  int d = blockIdx.x, b0 = blockIdx.y*16, f = threadIdx.x;
  __shared__ float wd_s[32][128];
  __shared__ float l_s[16][32];
  for (int c=0;c<32;c++) wd_s[c][f] = Wd[((i64)d*32+c)*128 + f];
  for (int l = f; l < 512; l += 128){ int bi=l>>5, c=l&31; l_s[bi][c] = left[(b0+bi)*32 + c]; }
  __syncthreads();
  float md = sm[d], obf = ob[f];
  for (int bi=0;bi<16;bi++){
    float acc = 0.f;
    #pragma unroll
    for (int c=0;c<32;c++) acc = fmaf(l_s[bi][c], wd_s[c][f], acc);
    int b = b0+bi;
    pa[((i64)d*256 + b)*128 + f] += (acc + obf) / (1e-3f + md*sm[b]);
  }
}

// ---------------- row attention core ----------------
__global__ __launch_bounds__(256) void ra_attn_k(const float* __restrict__ q, const float* __restrict__ k,
                                                 const float* __restrict__ v, const float* __restrict__ nb,
                                                 const float* __restrict__ sm, float* __restrict__ wa){
  int qi = blockIdx.x, h = blockIdx.y, tid = threadIdx.x;
  __shared__ float qv[48];
  __shared__ float p[256];
  __shared__ float red[256];
  if (tid < 48) qv[tid] = q[(i64)qi*384 + h*48 + tid];
  __syncthreads();
  float acc = 0.f;
  const float* kr = k + (i64)tid*384 + h*48;
  #pragma unroll
  for (int c=0;c<48;c++) acc = fmaf(qv[c], kr[c], acc);
  acc += 1e9f*(sm[tid]-1.f) + nb[((i64)qi*256 + tid)*8 + h];
  red[tid] = acc; __syncthreads();
  for (int off=128;off>0;off>>=1){ if (tid<off) red[tid] = fmaxf(red[tid], red[tid+off]); __syncthreads(); }
  float mx = red[0]; __syncthreads();
  float e = expf(acc - mx);
  red[tid] = e; __syncthreads();
  for (int off=128;off>0;off>>=1){ if (tid<off) red[tid] += red[tid+off]; __syncthreads(); }
  p[tid] = e / red[0];
  __syncthreads();
  if (tid < 48){
    float a = 0.f;
    for (int kk=0;kk<256;kk++) a = fmaf(p[kk], v[(i64)kk*384 + h*48 + tid], a);
    wa[(i64)qi*384 + h*48 + tid] = a;
  }
}

// ---------------- triangle attention core v3: double-buffered K/V prefetch ----------------
__global__ __launch_bounds__(128) void ta_attn_k(
    const float* __restrict__ q, const float* __restrict__ k, const float* __restrict__ v,
    const float* __restrict__ nbT, const float* __restrict__ mask, int maskT,
    float* __restrict__ wa)
{
  int b = blockIdx.x, h = blockIdx.y, tid = threadIdx.x;
  int q0 = tid, q1 = tid + 128;
  const i64 headoff = ((i64)b*256)*128 + h*32;
  const float* qp = q + headoff;
  const float* kp = k + headoff;
  const float* vp = v + headoff;
  const float* nbh = nbT + (i64)h*65536;

  float Q0[32], Q1[32];
  #pragma unroll
  for (int cc = 0; cc < 32; cc += 4){
    float4 a = *(const float4*)(qp + (i64)q0*128 + cc);
    Q0[cc]=a.x; Q0[cc+1]=a.y; Q0[cc+2]=a.z; Q0[cc+3]=a.w;
    float4 bb = *(const float4*)(qp + (i64)q1*128 + cc);
    Q1[cc]=bb.x; Q1[cc+1]=bb.y; Q1[cc+2]=bb.z; Q1[cc+3]=bb.w;
  }
  float acc0[32], acc1[32];
  #pragma unroll
  for (int c = 0; c < 32; c++){ acc0[c]=0.f; acc1[c]=0.f; }
  float m0=-1e30f, m1=-1e30f, l0=0.f, l1=0.f;

  __shared__ float Ks[2][16][32];
  __shared__ float Vs[2][16][32];
  int r = tid >> 3, c4 = (tid & 7) * 4;

  float4 kpre = *(const float4*)(kp + (i64)r*128 + c4);
  float4 vpre = *(const float4*)(vp + (i64)r*128 + c4);
  *(float4*)&Ks[0][r][c4] = kpre;
  *(float4*)&Vs[0][r][c4] = vpre;
  __syncthreads();

  for (int t = 0; t < 16; t++){
    int cur = t & 1;
    if (t < 15){
      kpre = *(const float4*)(kp + (i64)((t+1)*16 + r)*128 + c4);
      vpre = *(const float4*)(vp + (i64)((t+1)*16 + r)*128 + c4);
    }
    #pragma unroll
    for (int g = 0; g < 2; g++){
      float s0[8], s1[8];
      #pragma unroll
      for (int j = 0; j < 8; j++){
        int kl = g*8 + j;
        float d0=0.f, d1=0.f;
        #pragma unroll
        for (int cc = 0; cc < 32; cc += 4){
          float4 kv = *(const float4*)&Ks[cur][kl][cc];
          d0 = fmaf(Q0[cc],kv.x,d0); d0 = fmaf(Q0[cc+1],kv.y,d0);
          d0 = fmaf(Q0[cc+2],kv.z,d0); d0 = fmaf(Q0[cc+3],kv.w,d0);
          d1 = fmaf(Q1[cc],kv.x,d1); d1 = fmaf(Q1[cc+1],kv.y,d1);
          d1 = fmaf(Q1[cc+2],kv.z,d1); d1 = fmaf(Q1[cc+3],kv.w,d1);
        }
        int kk = t*16 + kl;
        float mv = maskT ? mask[(i64)kk*256 + b] : mask[(i64)b*256 + kk];
        float bias = 1e9f*(mv - 1.f);
        s0[j] = d0 + bias + nbh[(i64)kk*256 + q0];
        s1[j] = d1 + bias + nbh[(i64)kk*256 + q1];
      }
      float nm0=m0, nm1=m1;
      #pragma unroll
      for (int j=0;j<8;j++){ nm0 = fmaxf(nm0, s0[j]); nm1 = fmaxf(nm1, s1[j]); }
      float a0 = __expf(m0-nm0), a1 = __expf(m1-nm1);
      m0=nm0; m1=nm1; l0*=a0; l1*=a1;
      #pragma unroll
      for (int c=0;c<32;c++){ acc0[c]*=a0; acc1[c]*=a1; }
      #pragma unroll
      for (int j=0;j<8;j++){
        int kl = g*8 + j;
        float p0 = __expf(s0[j]-m0), p1 = __expf(s1[j]-m1);
        l0 += p0; l1 += p1;
        #pragma unroll
        for (int cc=0; cc<32; cc+=4){
          float4 vv = *(const float4*)&Vs[cur][kl][cc];
          acc0[cc]  += p0*vv.x; acc0[cc+1]+= p0*vv.y; acc0[cc+2]+= p0*vv.z; acc0[cc+3]+= p0*vv.w;
          acc1[cc]  += p1*vv.x; acc1[cc+1]+= p1*vv.y; acc1[cc+2]+= p1*vv.z; acc1[cc+3]+= p1*vv.w;
        }
      }
    }
    __syncthreads();
    if (t < 15){
      *(float4*)&Ks[cur^1][r][c4] = kpre;
      *(float4*)&Vs[cur^1][r][c4] = vpre;
    }
    __syncthreads();
  }
  float i0 = 1.f/l0, i1 = 1.f/l1;
  float* w0 = wa + headoff + (i64)q0*128;
  float* w1 = wa + headoff + (i64)q1*128;
  #pragma unroll
  for (int cc=0; cc<32; cc+=4){
    *(float4*)(w0+cc) = make_float4(acc0[cc]*i0, acc0[cc+1]*i0, acc0[cc+2]*i0, acc0[cc+3]*i0);
    *(float4*)(w1+cc) = make_float4(acc1[cc]*i1, acc1[cc+1]*i1, acc1[cc+2]*i1, acc1[cc+3]*i1);
  }
}

// ---------------- host dispatch ----------------
static void gemm(hipStream_t st, bool TA, bool TB,
                 const float* A, int lda, i64 sA,
                 const float* B, int ldb, i64 sB,
                 float* C, int ldc, i64 sC,
                 int M, int N, int K, int batch,
                 const float* bias, float scale, int act,
                 const float* rowmul, int combine)
{
  dim3 g((M+63)/64, (N+63)/64, batch), bl(256);
  if (!TA && !TB)      gemm_k<false,false><<<g,bl,0,st>>>(A,lda,sA,B,ldb,sB,C,ldc,sC,M,N,K,bias,scale,act,rowmul,combine);
  else if (!TA &&  TB) gemm_k<false,true ><<<g,bl,0,st>>>(A,lda,sA,B,ldb,sB,C,ldc,sC,M,N,K,bias,scale,act,rowmul,combine);
  else                 gemm_k<true ,false><<<g,bl,0,st>>>(A,lda,sA,B,ldb,sB,C,ldc,sC,M,N,K,bias,scale,act,rowmul,combine);
}

static void mgemm(hipStream_t st, bool TA, bool TB,
                  const float* A, int lda, i64 sA,
                  const float* B, int ldb, i64 sB,
                  float* C, int ldc, i64 sC,
                  int M, int N, int K, int batch,
                  const float* bias, float scale, int act,
                  const float* rowmul, int combine)
{
  dim3 g(M/128, N/128, batch), bl(256);
  if (!TA && !TB)      mgemm_k<false,false><<<g,bl,0,st>>>(A,lda,sA,B,ldb,sB,C,ldc,sC,M,N,K,bias,scale,act,rowmul,combine);
  else if (!TA &&  TB) mgemm_k<false,true ><<<g,bl,0,st>>>(A,lda,sA,B,ldb,sB,C,ldc,sC,M,N,K,bias,scale,act,rowmul,combine);
  else                 mgemm_k<true ,false><<<g,bl,0,st>>>(A,lda,sA,B,ldb,sB,C,ldc,sC,M,N,K,bias,scale,act,rowmul,combine);
}

static void gemm_thin(hipStream_t st,
                      const float* A, int lda, const float* B, int ldb,
                      float* C, int ldc, int M, int N, int K,
                      const float* bias, float scale, int act,
                      const float* rowmul, int combine, float* part)
{
  const int S = 8;
  int chunk = ((K/S + 15)/16)*16; if (chunk < 16) chunk = 16;
  dim3 g((M+15)/16, (N+63)/64, S);
  gemm_part_k<<<g,256,0,st>>>(A,lda,B,ldb,part,M,N,K,chunk);
  i64 t = (i64)M*N;
  gemm_reduce_k<<<(int)((t+255)/256),256,0,st>>>(part,C,ldc,M,N,S,bias,scale,act,rowmul,combine);
}

extern "C" void kernel_launch(void* const* d_in, const int* in_sizes, int n_in,
                              void* d_out, int out_size, void* d_ws, size_t ws_size,
                              hipStream_t stream)
{
  const float* IN[64];
  for (int i=0;i<n_in && i<64;i++) IN[i] = (const float*)d_in[i];

  const float* single_act = IN[0];
  const float* pair_act   = IN[1];
  const float* sm         = IN[2];
  const float* pm         = IN[3];
  const float* opm_ln     = IN[4];
  const float* opm_lr_w   = IN[5];
  const float* opm_lr_b   = IN[6];
  const float* opm_out_w  = IN[7];
  const float* opm_out_b  = IN[8];
  const float* ra_ln      = IN[9];
  const float* ra_pair_ln = IN[10];
  const float* ra_feat_w  = IN[11];
  const float* ra_qkv_w   = IN[12];
  const float* ra_gate_w  = IN[13];
  const float* ra_gate_b  = IN[14];
  const float* ra_o_w     = IN[15];
  const float* ra_o_b     = IN[16];
  const float* st_ln      = IN[17];
  const float* st_w1      = IN[18];
  const float* st_b1      = IN[19];
  const float* st_w2      = IN[20];
  const float* st_b2      = IN[21];
  const float* pt_ln      = IN[56];
  const float* pt_w1      = IN[57];
  const float* pt_b1      = IN[58];
  const float* pt_w2      = IN[59];
  const float* pt_b2      = IN[60];

  float* sa = (float*)d_out;           // [256,384]
  float* pa = (float*)d_out + 98304;   // [256,256,128]

  float* W  = (float*)d_ws;
  float* B0 = W;
  float* B1 = W + 8388608L;
  float* B2 = W + 16777216L;
  float* B3 = W + 25165824L;
  float* SMA = W + 33554432L;
  float* xs   = SMA;
  float* qb   = SMA +  98304;
  float* kb   = SMA + 196608;
  float* vb   = SMA + 294912;
  float* wab  = SMA + 393216;
  float* hst  = SMA + 491520;   // 393216
  float* nbra = SMA + 884736;   // 524288 (reused as nbT in tri-attn phase)
  float* lbuf = SMA + 1409024;  // 8192
  float* rbuf = SMA + 1417216;  // 8192
  float* Wd   = SMA + 1425408;  // 1048576
  float* nbt  = SMA + 2473984;  // 262144

  // init outputs with residual bases
  copy_k<<<384, 256, 0, stream>>>(sa, single_act, 98304L);
  copy_k<<<32768, 256, 0, stream>>>(pa, pair_act, 8388608L);

  // ---- 1) OPM -> pair residual ----
  ln_k<<<256,128,0,stream>>>(single_act, xs, opm_ln, 384);
  gemm_thin(stream, xs,384, opm_lr_w,32,       lbuf,32, 256,32,384, opm_lr_b,    1.f,0, sm,0, B1);
  gemm_thin(stream, xs,384, opm_lr_w+12288,32, rbuf,32, 256,32,384, opm_lr_b+32, 1.f,0, sm,0, B1);
  opm_wd_k<<<dim3(256,32),128,0,stream>>>(rbuf, opm_out_w, Wd);
  opm_final_k<<<dim3(256,16),128,0,stream>>>(lbuf, Wd, opm_out_b, sm, pa);

  // ---- 2) row attention with pair bias ----
  ln_k<<<256,128,0,stream>>>(sa, xs, ra_ln, 384);
  ln_k<<<65536,128,0,stream>>>(pa, B0, ra_pair_ln, 128);
  gemm(stream,false,false, B0,128,0, ra_feat_w,8,0, nbra,8,0, 65536,8,128,1, nullptr,1.f,0,nullptr,0);
  const float qs_ra = 0.14433756729740643f; // 1/sqrt(48)
  gemm_thin(stream, xs,384, ra_qkv_w,384,        qb,384, 256,384,384, nullptr,qs_ra,0,nullptr,0, B1);
  gemm_thin(stream, xs,384, ra_qkv_w+147456,384, kb,384, 256,384,384, nullptr,1.f,0,nullptr,0, B1);
  gemm_thin(stream, xs,384, ra_qkv_w+294912,384, vb,384, 256,384,384, nullptr,1.f,0,nullptr,0, B1);
  ra_attn_k<<<dim3(256,8),256,0,stream>>>(qb, kb, vb, nbra, sm, wab);
  gemm_thin(stream, xs,384,  ra_gate_w,384, wab,384, 256,384,384, ra_gate_b,1.f,2,nullptr,2, B1);
  gemm_thin(stream, wab,384, ra_o_w,384,    sa,384,  256,384,384, ra_o_b,   1.f,0,nullptr,1, B1);

  // ---- 3) single transition ----
  ln_k<<<256,128,0,stream>>>(sa, xs, st_ln, 384);
  gemm_thin(stream, xs,384,   st_w1,1536, hst,1536, 256,1536,384, st_b1,1.f,1,nullptr,0, B1);
  gemm_thin(stream, hst,1536, st_w2,384,  sa,384,   256,384,1536, st_b2,1.f,0,nullptr,1, B1);

  // ---- 4/5) triangle multiplications ----
  auto tri_mult = [&](int base, bool outgoing){
    const float* ln_w = IN[base+0];
    const float* lr_w = IN[base+1];
    const float* lr_b = IN[base+2];
    const float* gw   = IN[base+3];
    const float* gb   = IN[base+4];
    const float* cln  = IN[base+5];
    const float* ow   = IN[base+6];
    const float* ob   = IN[base+7];
    const float* ogw  = IN[base+8];
    const float* ogb  = IN[base+9];
    ln_k<<<65536,128,0,stream>>>(pa, B0, ln_w, 128);
    // left = mask * (X@Wl+bl) * sigmoid(X@Wg+bg): fused dual-MFMA, then transpose+mask -> B1 (ch-major)
    mlrgate_k<<<512,256,0,stream>>>(B0, lr_w, lr_b, gw, gb, B3);
    tr_mask_k<<<dim3(2048,4),256,0,stream>>>(B3, pm, B1);
    // right -> B2 (ch-major)
    mlrgate_k<<<512,256,0,stream>>>(B0, lr_w+16384, lr_b+128, gw+16384, gb+128, B3);
    tr_mask_k<<<dim3(2048,4),256,0,stream>>>(B3, pm, B2);
    if (outgoing) // out[i,j,c] = sum_k L_c[i,k] * R_c[j,k]
      mgemm(stream,false,true, B1,256,65536, B2,256,65536, B3,256,65536, 256,256,256,128, nullptr,1.f,0,nullptr,0);
    else          // out[i,j,c] = sum_k R_c[k,i] * L_c[k,j]
      mgemm(stream,true,false, B2,256,65536, B1,256,65536, B3,256,65536, 256,256,256,128, nullptr,1.f,0,nullptr,0);
    chw2hwc_k<<<dim3(2048,4),256,0,stream>>>(B3, B1);
    ln_k<<<65536,128,0,stream>>>(B1, B3, cln, 128);
    mgemm(stream,false,false, B3,128,0, ow,128,0,  B1,128,0, 65536,128,128,1, ob,  1.f,0,nullptr,0);
    mgemm(stream,false,false, B0,128,0, ogw,128,0, B3,128,0, 65536,128,128,1, ogb, 1.f,2,nullptr,0);
    muladd_k<<<32768,256,0,stream>>>(pa, B1, B3, 8388608L);
  };
  tri_mult(22, true);   // tmo
  tri_mult(32, false);  // tmi

  // ---- 6/7) triangle attentions ----
  auto tri_attn = [&](int base, bool percol){
    const float* ln_w   = IN[base+0];
    const float* feat_w = IN[base+1];
    const float* qkv_w  = IN[base+2];
    const float* gw     = IN[base+3];
    const float* gb     = IN[base+4];
    const float* ow     = IN[base+5];
    const float* ob     = IN[base+6];
    const float* src = pa;
    if (percol){ transpose_pair_k<<<65536,128,0,stream>>>(B1, pa); src = B1; }
    ln_k<<<65536,128,0,stream>>>(src, B0, ln_w, 128);
    gemm(stream,false,false, B0,128,0, feat_w,4,0, nbt,4,0, 65536,4,128,1, nullptr,1.f,0,nullptr,0);
    nbT_k<<<256,256,0,stream>>>(nbt, nbra);  // nbT[h][k][q]
    const float qs = 0.17677669529663687f; // 1/sqrt(32)
    mgemm(stream,false,false, B0,128,0, qkv_w,128,0,       B1,128,0, 65536,128,128,1, nullptr,qs, 0,nullptr,0);
    mgemm(stream,false,false, B0,128,0, qkv_w+16384,128,0, B2,128,0, 65536,128,128,1, nullptr,1.f,0,nullptr,0);
    mgemm(stream,false,false, B0,128,0, qkv_w+32768,128,0, B3,128,0, 65536,128,128,1, nullptr,1.f,0,nullptr,0);
    ta_attn_k<<<dim3(256,4),128,0,stream>>>(B1, B2, B3, nbra, pm, percol?1:0, B1);
    mgemm(stream,false,false, B0,128,0, gw,128,0, B1,128,0, 65536,128,128,1, gb,1.f,2,nullptr,2); // wa *= sigmoid(gate)
    mgemm(stream,false,false, B1,128,0, ow,128,0, B2,128,0, 65536,128,128,1, ob,1.f,0,nullptr,0);
    resadd_k<<<65536,128,0,stream>>>(pa, B2, percol?1:0);
  };
  tri_attn(42, false);  // tas (per-row)
  tri_attn(49, true);   // tae (per-column)

  // ---- 8) pair transition ----
  ln_k<<<65536,128,0,stream>>>(pa, B0, pt_ln, 128);
  for (int half = 0; half < 2; half++){
    const float* xh = B0 + (i64)half*4194304;
    float* ph = pa + (i64)half*4194304;
    mgemm(stream,false,false, xh,128,0, pt_w1,512,0, B1,512,0, 32768,512,128,1, pt_b1,1.f,1,nullptr,0);
    mgemm(stream,false,false, B1,512,0, pt_w2,128,0, ph,128,0, 32768,128,512,1, pt_b2,1.f,0,nullptr,1);
  }
}

// Round 7
// 2117.988 us; speedup vs baseline: 3.3060x; 3.3060x over previous
//
#include <hip/hip_runtime.h>
#include <math.h>

typedef long long i64;
#define NN_ 65536L

typedef __attribute__((ext_vector_type(8))) short bf16x8;
typedef __attribute__((ext_vector_type(4))) float f32x4;

__device__ inline unsigned short f2bf(float f){
  unsigned int u = __float_as_uint(f);
  return (unsigned short)((u + 0x7FFFu + ((u>>16)&1u)) >> 16);
}

// ---------------- elementwise ----------------
__global__ __launch_bounds__(256) void copy_k(float* __restrict__ d, const float* __restrict__ s, long n){
  long i = (long)blockIdx.x*blockDim.x + threadIdx.x;
  if (i < n) d[i] = s[i];
}

__global__ __launch_bounds__(256) void muladd_k(float* __restrict__ d, const float* __restrict__ a,
                                                const float* __restrict__ b, long n){
  long i = (long)blockIdx.x*blockDim.x + threadIdx.x;
  if (i < n) d[i] += a[i]*b[i];
}

// out[j,i,:] = in[i,j,:]   (pair transpose, c contiguous both sides)
__global__ __launch_bounds__(128) void transpose_pair_k(float* __restrict__ out, const float* __restrict__ in){
  int blk = blockIdx.x; int i = blk >> 8, j = blk & 255; int c = threadIdx.x;
  out[((i64)(j*256+i))*128 + c] = in[((i64)blk)*128 + c];
}

// pa += src (optionally with (i,j)->(j,i) transpose of the block index)
__global__ __launch_bounds__(128) void resadd_k(float* __restrict__ pa, const float* __restrict__ src, int T){
  int blk = blockIdx.x; int c = threadIdx.x;
  float v = src[((i64)blk)*128 + c];
  i64 didx;
  if (T){ int i = blk>>8, j = blk&255; didx = ((i64)(j*256+i))*128 + c; }
  else didx = ((i64)blk)*128 + c;
  pa[didx] += v;
}

// channel-major [128][65536] -> row-major [65536][128]
__global__ __launch_bounds__(256) void chw2hwc_k(const float* __restrict__ in, float* __restrict__ out){
  __shared__ float t[32][33];
  int r0 = blockIdx.x*32, c0 = blockIdx.y*32;
  int tx = threadIdx.x & 31, ty = threadIdx.x >> 5;
  for (int i = ty; i < 32; i += 8) t[i][tx] = in[(i64)(c0+i)*NN_ + r0 + tx];
  __syncthreads();
  for (int i = ty; i < 32; i += 8) out[(i64)(r0+i)*128 + c0 + tx] = t[tx][i];
}

// row-major [65536][128] -> ch-major [128][65536] with per-row mask
__global__ __launch_bounds__(256) void tr_mask_k(const float* __restrict__ in, const float* __restrict__ mask,
                                                 float* __restrict__ out){
  __shared__ float t[32][33];
  int r0 = blockIdx.x*32, c0 = blockIdx.y*32;
  int tx = threadIdx.x & 31, ty = threadIdx.x >> 5;
  for (int i = ty; i < 32; i += 8) t[i][tx] = in[(i64)(r0+i)*128 + c0 + tx];
  __syncthreads();
  for (int i = ty; i < 32; i += 8) out[(i64)(c0+i)*NN_ + r0 + tx] = t[tx][i] * mask[r0+tx];
}

// nb [q,k,h=4] -> nbT [h][k][q]
__global__ __launch_bounds__(256) void nbT_k(const float* __restrict__ in, float* __restrict__ out){
  int kk = blockIdx.x, qq = threadIdx.x;
  float4 vv = *(const float4*)(in + ((i64)qq*256 + kk)*4);
  out[0*65536 + kk*256 + qq] = vv.x;
  out[1*65536 + kk*256 + qq] = vv.y;
  out[2*65536 + kk*256 + qq] = vv.z;
  out[3*65536 + kk*256 + qq] = vv.w;
}

// ---------------- LayerNorm (rowwise) ----------------
__global__ __launch_bounds__(128) void ln_k(const float* __restrict__ in, float* __restrict__ out,
                                            const float* __restrict__ w, int C){
  i64 row = blockIdx.x;
  const float* x = in + row*C;
  float* y = out + row*C;
  int tid = threadIdx.x;
  float s=0.f, s2=0.f;
  for (int c=tid;c<C;c+=128){ float v = x[c]; s += v; s2 += v*v; }
  __shared__ float rs[128], rq[128];
  rs[tid]=s; rq[tid]=s2; __syncthreads();
  for (int off=64;off>0;off>>=1){ if (tid<off){ rs[tid]+=rs[tid+off]; rq[tid]+=rq[tid+off]; } __syncthreads(); }
  float mu = rs[0]/C;
  float var = rq[0]/C - mu*mu;
  float inv = rsqrtf(var + 1e-5f);
  for (int c=tid;c<C;c+=128) y[c] = (x[c]-mu)*inv*w[c] + w[C+c];
}

// ---------------- bf16 MFMA GEMM: 128x128 tile, 256 thr (2x2 waves of 64x64) ----------------
template<bool TA, bool TB>
__global__ __launch_bounds__(256) void mgemm_k(
    const float* __restrict__ A, int lda, i64 sA,
    const float* __restrict__ B, int ldb, i64 sB,
    float* __restrict__ C, int ldc, i64 sC,
    int M, int N, int K,
    const float* __restrict__ bias, float scale, int act,
    const float* __restrict__ rowmul, int combine)
{
  A += (i64)blockIdx.z * sA;
  B += (i64)blockIdx.z * sB;
  C += (i64)blockIdx.z * sC;
  int m0 = blockIdx.x * 128, n0 = blockIdx.y * 128;
  int tid = threadIdx.x;
  int wave = tid >> 6, lane = tid & 63;
  int quad = lane >> 4, mr = lane & 15;
  int wm = (wave >> 1) * 64, wn = (wave & 1) * 64;
  __shared__ unsigned short As[128][40];
  __shared__ unsigned short Bs[128][40];
  f32x4 acc[4][4];
  #pragma unroll
  for (int i=0;i<4;i++)
    #pragma unroll
    for (int j=0;j<4;j++) acc[i][j] = (f32x4){0.f,0.f,0.f,0.f};

  for (int k0 = 0; k0 < K; k0 += 32){
    if (!TA){
      #pragma unroll
      for (int it=0; it<4; it++){
        int lin = tid + it*256;
        int r = lin >> 3, c4 = (lin & 7) * 4;
        float4 g = *(const float4*)&A[(i64)(m0+r)*lda + k0 + c4];
        As[r][c4]   = f2bf(g.x); As[r][c4+1] = f2bf(g.y);
        As[r][c4+2] = f2bf(g.z); As[r][c4+3] = f2bf(g.w);
      }
    } else {
      #pragma unroll
      for (int it=0; it<4; it++){
        int lin = tid + it*256;
        int m = lin & 127, kg = (lin >> 7) * 4;
        float v0 = A[(i64)(k0+kg  )*lda + m0 + m];
        float v1 = A[(i64)(k0+kg+1)*lda + m0 + m];
        float v2 = A[(i64)(k0+kg+2)*lda + m0 + m];
        float v3 = A[(i64)(k0+kg+3)*lda + m0 + m];
        As[m][kg] = f2bf(v0); As[m][kg+1] = f2bf(v1);
        As[m][kg+2] = f2bf(v2); As[m][kg+3] = f2bf(v3);
      }
    }
    if (!TB){
      #pragma unroll
      for (int it=0; it<4; it++){
        int lin = tid + it*256;
        int n = lin & 127, kg = (lin >> 7) * 4;
        float v0 = B[(i64)(k0+kg  )*ldb + n0 + n];
        float v1 = B[(i64)(k0+kg+1)*ldb + n0 + n];
        float v2 = B[(i64)(k0+kg+2)*ldb + n0 + n];
        float v3 = B[(i64)(k0+kg+3)*ldb + n0 + n];
        Bs[n][kg] = f2bf(v0); Bs[n][kg+1] = f2bf(v1);
        Bs[n][kg+2] = f2bf(v2); Bs[n][kg+3] = f2bf(v3);
      }
    } else {
      #pragma unroll
      for (int it=0; it<4; it++){
        int lin = tid + it*256;
        int r = lin >> 3, c4 = (lin & 7) * 4;
        float4 g = *(const float4*)&B[(i64)(n0+r)*ldb + k0 + c4];
        Bs[r][c4]   = f2bf(g.x); Bs[r][c4+1] = f2bf(g.y);
        Bs[r][c4+2] = f2bf(g.z); Bs[r][c4+3] = f2bf(g.w);
      }
    }
    __syncthreads();
    bf16x8 af[4], bfr[4];
    #pragma unroll
    for (int i=0;i<4;i++) af[i]  = *(const bf16x8*)&As[wm + i*16 + mr][quad*8];
    #pragma unroll
    for (int j=0;j<4;j++) bfr[j] = *(const bf16x8*)&Bs[wn + j*16 + mr][quad*8];
    #pragma unroll
    for (int i=0;i<4;i++)
      #pragma unroll
      for (int j=0;j<4;j++)
        acc[i][j] = __builtin_amdgcn_mfma_f32_16x16x32_bf16(af[i], bfr[j], acc[i][j], 0, 0, 0);
    __syncthreads();
  }
  #pragma unroll
  for (int i=0;i<4;i++){
    #pragma unroll
    for (int r=0;r<4;r++){
      int m = m0 + wm + i*16 + quad*4 + r;
      float rm = rowmul ? rowmul[m] : 1.f;
      #pragma unroll
      for (int j=0;j<4;j++){
        int n = n0 + wn + j*16 + mr;
        float v = acc[i][j][r] * scale;
        if (bias) v += bias[n];
        if (act == 1) v = fmaxf(v, 0.f);
        else if (act == 2) v = 1.f/(1.f + __expf(-v));
        v *= rm;
        i64 idx = (i64)m*ldc + n;
        if (combine == 0) C[idx] = v;
        else if (combine == 1) C[idx] += v;
        else C[idx] *= v;
      }
    }
  }
}

// ---------------- fused dual-MFMA lin*sigmoid(gate) for tri-mult (M=65536, N=128, K=128) ----------------
__global__ __launch_bounds__(256) void mlrgate_k(
    const float* __restrict__ X,
    const float* __restrict__ Wl, const float* __restrict__ bl,
    const float* __restrict__ Wg, const float* __restrict__ bg,
    float* __restrict__ Out)
{
  int m0 = blockIdx.x * 128;
  int tid = threadIdx.x;
  int wave = tid >> 6, lane = tid & 63;
  int quad = lane >> 4, mr = lane & 15;
  int wm = (wave >> 1) * 64, wn = (wave & 1) * 64;
  __shared__ unsigned short As[128][40], B1s[128][40], B2s[128][40];
  f32x4 acc1[4][4], acc2[4][4];
  #pragma unroll
  for (int i=0;i<4;i++)
    #pragma unroll
    for (int j=0;j<4;j++){ acc1[i][j] = (f32x4){0,0,0,0}; acc2[i][j] = (f32x4){0,0,0,0}; }

  for (int k0 = 0; k0 < 128; k0 += 32){
    #pragma unroll
    for (int it=0; it<4; it++){
      int lin = tid + it*256;
      int r = lin >> 3, c4 = (lin & 7) * 4;
      float4 g = *(const float4*)&X[(i64)(m0+r)*128 + k0 + c4];
      As[r][c4]   = f2bf(g.x); As[r][c4+1] = f2bf(g.y);
      As[r][c4+2] = f2bf(g.z); As[r][c4+3] = f2bf(g.w);
    }
    #pragma unroll
    for (int it=0; it<4; it++){
      int lin = tid + it*256;
      int n = lin & 127, kg = (lin >> 7) * 4;
      float a0 = Wl[(i64)(k0+kg  )*128 + n];
      float a1 = Wl[(i64)(k0+kg+1)*128 + n];
      float a2 = Wl[(i64)(k0+kg+2)*128 + n];
      float a3 = Wl[(i64)(k0+kg+3)*128 + n];
      B1s[n][kg] = f2bf(a0); B1s[n][kg+1] = f2bf(a1);
      B1s[n][kg+2] = f2bf(a2); B1s[n][kg+3] = f2bf(a3);
      float g0 = Wg[(i64)(k0+kg  )*128 + n];
      float g1 = Wg[(i64)(k0+kg+1)*128 + n];
      float g2 = Wg[(i64)(k0+kg+2)*128 + n];
      float g3 = Wg[(i64)(k0+kg+3)*128 + n];
      B2s[n][kg] = f2bf(g0); B2s[n][kg+1] = f2bf(g1);
      B2s[n][kg+2] = f2bf(g2); B2s[n][kg+3] = f2bf(g3);
    }
    __syncthreads();
    bf16x8 af[4], b1f[4], b2f[4];
    #pragma unroll
    for (int i=0;i<4;i++) af[i]  = *(const bf16x8*)&As[wm + i*16 + mr][quad*8];
    #pragma unroll
    for (int j=0;j<4;j++){
      b1f[j] = *(const bf16x8*)&B1s[wn + j*16 + mr][quad*8];
      b2f[j] = *(const bf16x8*)&B2s[wn + j*16 + mr][quad*8];
    }
    #pragma unroll
    for (int i=0;i<4;i++)
      #pragma unroll
      for (int j=0;j<4;j++){
        acc1[i][j] = __builtin_amdgcn_mfma_f32_16x16x32_bf16(af[i], b1f[j], acc1[i][j], 0, 0, 0);
        acc2[i][j] = __builtin_amdgcn_mfma_f32_16x16x32_bf16(af[i], b2f[j], acc2[i][j], 0, 0, 0);
      }
    __syncthreads();
  }
  #pragma unroll
  for (int i=0;i<4;i++){
    #pragma unroll
    for (int r=0;r<4;r++){
      int m = m0 + wm + i*16 + quad*4 + r;
      #pragma unroll
      for (int j=0;j<4;j++){
        int n = wn + j*16 + mr;
        float lv = acc1[i][j][r] + bl[n];
        float gv = acc2[i][j][r] + bg[n];
        Out[(i64)m*128 + n] = lv * (1.f/(1.f + __expf(-gv)));
      }
    }
  }
}

// ---------------- generic batched GEMM (fp32, 64x64 tile) ----------------
template<bool TA, bool TB>
__global__ __launch_bounds__(256) void gemm_k(
    const float* __restrict__ A, int lda, i64 sA,
    const float* __restrict__ B, int ldb, i64 sB,
    float* __restrict__ C, int ldc, i64 sC,
    int M, int N, int K,
    const float* __restrict__ bias, float scale, int act,
    const float* __restrict__ rowmul, int combine)
{
  A += (i64)blockIdx.z * sA;
  B += (i64)blockIdx.z * sB;
  C += (i64)blockIdx.z * sC;
  int m0 = blockIdx.x * 64, n0 = blockIdx.y * 64;
  int tid = threadIdx.x, tx = tid & 15, ty = tid >> 4;
  __shared__ float As[16][68], Bs[16][68];
  float acc[4][4] = {};
  for (int k0 = 0; k0 < K; k0 += 16){
    if (TA){
      for (int l = tid; l < 1024; l += 256){
        int kk = l >> 6, mi = l & 63; int m = m0 + mi;
        As[kk][mi] = (m < M) ? A[(i64)(k0+kk)*lda + m] : 0.f;
      }
    } else {
      for (int l = tid; l < 1024; l += 256){
        int mi = l >> 4, kk = l & 15; int m = m0 + mi;
        As[kk][mi] = (m < M) ? A[(i64)m*lda + k0 + kk] : 0.f;
      }
    }
    if (TB){
      for (int l = tid; l < 1024; l += 256){
        int ni = l >> 4, kk = l & 15; int n = n0 + ni;
        Bs[kk][ni] = (n < N) ? B[(i64)n*ldb + k0 + kk] : 0.f;
      }
    } else {
      for (int l = tid; l < 1024; l += 256){
        int kk = l >> 6, ni = l & 63; int n = n0 + ni;
        Bs[kk][ni] = (n < N) ? B[(i64)(k0+kk)*ldb + n] : 0.f;
      }
    }
    __syncthreads();
    #pragma unroll
    for (int kk = 0; kk < 16; ++kk){
      float4 av4 = *(const float4*)&As[kk][ty*4];
      float4 bv4 = *(const float4*)&Bs[kk][tx*4];
      float av[4] = {av4.x, av4.y, av4.z, av4.w};
      float bv[4] = {bv4.x, bv4.y, bv4.z, bv4.w};
      #pragma unroll
      for (int i=0;i<4;i++)
        #pragma unroll
        for (int j=0;j<4;j++) acc[i][j] = fmaf(av[i], bv[j], acc[i][j]);
    }
    __syncthreads();
  }
  #pragma unroll
  for (int i=0;i<4;i++){
    int m = m0 + ty*4 + i;
    if (m >= M) continue;
    float rm = rowmul ? rowmul[m] : 1.f;
    #pragma unroll
    for (int j=0;j<4;j++){
      int n = n0 + tx*4 + j;
      if (n >= N) continue;
      float v = acc[i][j] * scale;
      if (bias) v += bias[n];
      if (act == 1) v = fmaxf(v, 0.f);
      else if (act == 2) v = 1.f/(1.f + expf(-v));
      v *= rm;
      i64 idx = (i64)m*ldc + n;
      if (combine == 0) C[idx] = v;
      else if (combine == 1) C[idx] += v;
      else C[idx] *= v;
    }
  }
}

// ---------------- thin GEMM (small M): split-K two-phase ----------------
__global__ __launch_bounds__(256) void gemm_part_k(
    const float* __restrict__ A, int lda,
    const float* __restrict__ B, int ldb,
    float* __restrict__ Cp, int M, int N, int K, int chunk)
{
  int m0 = blockIdx.x*16, n0 = blockIdx.y*64, z = blockIdx.z;
  int kb = z*chunk, ke = min(K, kb+chunk);
  int tid = threadIdx.x;
  int mi = tid >> 4, ni4 = (tid & 15)*4;
  __shared__ float As[16][17], Bs[16][68];
  float acc[4] = {0.f,0.f,0.f,0.f};
  for (int k0 = kb; k0 < ke; k0 += 16){
    { int r = tid>>4, c = tid&15; int m = m0+r;
      As[c][r] = (m < M) ? A[(i64)m*lda + k0 + c] : 0.f; }
    for (int l = tid; l < 1024; l += 256){
      int kk = l>>6, nn = l&63; int n = n0+nn;
      Bs[kk][nn] = (n < N) ? B[(i64)(k0+kk)*ldb + n] : 0.f;
    }
    __syncthreads();
    #pragma unroll
    for (int kk=0;kk<16;kk++){
      float a = As[kk][mi];
      float4 b = *(const float4*)&Bs[kk][ni4];
      acc[0]=fmaf(a,b.x,acc[0]); acc[1]=fmaf(a,b.y,acc[1]);
      acc[2]=fmaf(a,b.z,acc[2]); acc[3]=fmaf(a,b.w,acc[3]);
    }
    __syncthreads();
  }
  int m = m0+mi, n = n0+ni4;
  if (m < M && n < N) *(float4*)&Cp[((i64)z*M + m)*N + n] = *(float4*)acc;
}

__global__ __launch_bounds__(256) void gemm_reduce_k(
    const float* __restrict__ Cp, float* __restrict__ C, int ldc,
    int M, int N, int S,
    const float* __restrict__ bias, float scale, int act,
    const float* __restrict__ rowmul, int combine)
{
  i64 idx = (i64)blockIdx.x*256 + threadIdx.x;
  if (idx >= (i64)M*N) return;
  int m = (int)(idx / N), n = (int)(idx % N);
  float s = 0.f;
  for (int z=0; z<S; z++) s += Cp[(i64)z*M*N + idx];
  float v = s*scale;
  if (bias) v += bias[n];
  if (act == 1) v = fmaxf(v, 0.f);
  else if (act == 2) v = 1.f/(1.f + expf(-v));
  if (rowmul) v *= rowmul[m];
  i64 o = (i64)m*ldc + n;
  if (combine == 0) C[o] = v;
  else if (combine == 1) C[o] += v;
  else C[o] *= v;
}

// ---------------- OPM ----------------
__global__ __launch_bounds__(128) void opm_wd_k(const float* __restrict__ right, const float* __restrict__ W,
                                                float* __restrict__ Wd){
  int d = blockIdx.x, c = blockIdx.y, f = threadIdx.x;
  float acc = 0.f;
  #pragma unroll
  for (int e=0;e<32;e++) acc = fmaf(right[d*32+e], W[((i64)c*32+e)*128 + f], acc);
  Wd[((i64)d*32+c)*128 + f] = acc;
}

__global__ __launch_bounds__(128) void opm_final_k(const float* __restrict__ left, const float* __restrict__ Wd,
                                                   const float* __restrict__ ob, const float* __restrict__ sm,
                                                   float* __restrict__ pa){
  int d = blockIdx.x, b0 = blockIdx.y*16, f = threadIdx.x;
  __shared__ float wd_s[32][128];
  __shared__ float l_s[16][32];
  for (int c=0;c<32;c++) wd_s[c][f] = Wd[((i64)d*32+c)*128 + f];
  for (int l = f; l < 512; l += 128){ int bi=l>>5, c=l&31; l_s[bi][c] = left[(b0+bi)*32 + c]; }
  __syncthreads();
  float md = sm[d], obf = ob[f];
  for (int bi=0;bi<16;bi++){
    float acc = 0.f;
    #pragma unroll
    for (int c=0;c<32;c++) acc = fmaf(l_s[bi][c], wd_s[c][f], acc);
    int b = b0+bi;
    pa[((i64)d*256 + b)*128 + f] += (acc + obf) / (1e-3f + md*sm[b]);
  }
}

// ---------------- row attention core ----------------
__global__ __launch_bounds__(256) void ra_attn_k(const float* __restrict__ q, const float* __restrict__ k,
                                                 const float* __restrict__ v, const float* __restrict__ nb,
                                                 const float* __restrict__ sm, float* __restrict__ wa){
  int qi = blockIdx.x, h = blockIdx.y, tid = threadIdx.x;
  __shared__ float qv[48];
  __shared__ float p[256];
  __shared__ float red[256];
  if (tid < 48) qv[tid] = q[(i64)qi*384 + h*48 + tid];
  __syncthreads();
  float acc = 0.f;
  const float* kr = k + (i64)tid*384 + h*48;
  #pragma unroll
  for (int c=0;c<48;c++) acc = fmaf(qv[c], kr[c], acc);
  acc += 1e9f*(sm[tid]-1.f) + nb[((i64)qi*256 + tid)*8 + h];
  red[tid] = acc; __syncthreads();
  for (int off=128;off>0;off>>=1){ if (tid<off) red[tid] = fmaxf(red[tid], red[tid+off]); __syncthreads(); }
  float mx = red[0]; __syncthreads();
  float e = expf(acc - mx);
  red[tid] = e; __syncthreads();
  for (int off=128;off>0;off>>=1){ if (tid<off) red[tid] += red[tid+off]; __syncthreads(); }
  p[tid] = e / red[0];
  __syncthreads();
  if (tid < 48){
    float a = 0.f;
    for (int kk=0;kk<256;kk++) a = fmaf(p[kk], v[(i64)kk*384 + h*48 + tid], a);
    wa[(i64)qi*384 + h*48 + tid] = a;
  }
}

// ---------------- triangle attention core v4: 1 q-row/thread, 256 thr (4 waves) ----------------
// Reverted to v2 dataflow (8-row LDS K/V tiles, no register prefetch — v3's prefetch spilled).
// 256 threads halve per-thread registers (Q[32]+acc[32]) and double waves/block for latency hiding.
__global__ __launch_bounds__(256) void ta_attn_k(
    const float* __restrict__ q, const float* __restrict__ k, const float* __restrict__ v,
    const float* __restrict__ nbT, const float* __restrict__ mask, int maskT,
    float* __restrict__ wa)
{
  int b = blockIdx.x, h = blockIdx.y, tid = threadIdx.x;
  const i64 headoff = ((i64)b*256)*128 + h*32;
  const float* qp = q + headoff;
  const float* kp = k + headoff;
  const float* vp = v + headoff;
  const float* nbh = nbT + (i64)h*65536;

  float Q[32];
  #pragma unroll
  for (int cc = 0; cc < 32; cc += 4){
    float4 a = *(const float4*)(qp + (i64)tid*128 + cc);
    Q[cc]=a.x; Q[cc+1]=a.y; Q[cc+2]=a.z; Q[cc+3]=a.w;
  }
  float acc[32];
  #pragma unroll
  for (int c = 0; c < 32; c++) acc[c]=0.f;
  float mx=-1e30f, lsum=0.f;

  __shared__ float Ks[8][32];
  __shared__ float Vs[8][32];
  int r = tid >> 5, c = tid & 31;

  for (int kc = 0; kc < 256; kc += 8){
    __syncthreads();
    Ks[r][c] = kp[(i64)(kc+r)*128 + c];
    Vs[r][c] = vp[(i64)(kc+r)*128 + c];
    __syncthreads();
    float s[8];
    #pragma unroll
    for (int j = 0; j < 8; j++){
      float d = 0.f;
      #pragma unroll
      for (int cc = 0; cc < 32; cc += 4){
        float4 kv = *(const float4*)&Ks[j][cc];
        d = fmaf(Q[cc],kv.x,d); d = fmaf(Q[cc+1],kv.y,d);
        d = fmaf(Q[cc+2],kv.z,d); d = fmaf(Q[cc+3],kv.w,d);
      }
      int kk = kc + j;
      float mv = maskT ? mask[(i64)kk*256 + b] : mask[(i64)b*256 + kk];
      s[j] = d + 1e9f*(mv - 1.f) + nbh[(i64)kk*256 + tid];
    }
    float nm = mx;
    #pragma unroll
    for (int j=0;j<8;j++) nm = fmaxf(nm, s[j]);
    float alpha = __expf(mx-nm);
    mx = nm; lsum *= alpha;
    #pragma unroll
    for (int cc=0;cc<32;cc++) acc[cc] *= alpha;
    #pragma unroll
    for (int j=0;j<8;j++){
      float p = __expf(s[j]-mx);
      lsum += p;
      #pragma unroll
      for (int cc=0; cc<32; cc+=4){
        float4 vv = *(const float4*)&Vs[j][cc];
        acc[cc]  += p*vv.x; acc[cc+1]+= p*vv.y; acc[cc+2]+= p*vv.z; acc[cc+3]+= p*vv.w;
      }
    }
  }
  float inv = 1.f/lsum;
  float* w0 = wa + headoff + (i64)tid*128;
  #pragma unroll
  for (int cc=0; cc<32; cc+=4)
    *(float4*)(w0+cc) = make_float4(acc[cc]*inv, acc[cc+1]*inv, acc[cc+2]*inv, acc[cc+3]*inv);
}

// ---------------- host dispatch ----------------
static void gemm(hipStream_t st, bool TA, bool TB,
                 const float* A, int lda, i64 sA,
                 const float* B, int ldb, i64 sB,
                 float* C, int ldc, i64 sC,
                 int M, int N, int K, int batch,
                 const float* bias, float scale, int act,
                 const float* rowmul, int combine)
{
  dim3 g((M+63)/64, (N+63)/64, batch), bl(256);
  if (!TA && !TB)      gemm_k<false,false><<<g,bl,0,st>>>(A,lda,sA,B,ldb,sB,C,ldc,sC,M,N,K,bias,scale,act,rowmul,combine);
  else if (!TA &&  TB) gemm_k<false,true ><<<g,bl,0,st>>>(A,lda,sA,B,ldb,sB,C,ldc,sC,M,N,K,bias,scale,act,rowmul,combine);
  else                 gemm_k<true ,false><<<g,bl,0,st>>>(A,lda,sA,B,ldb,sB,C,ldc,sC,M,N,K,bias,scale,act,rowmul,combine);
}

static void mgemm(hipStream_t st, bool TA, bool TB,
                  const float* A, int lda, i64 sA,
                  const float* B, int ldb, i64 sB,
                  float* C, int ldc, i64 sC,
                  int M, int N, int K, int batch,
                  const float* bias, float scale, int act,
                  const float* rowmul, int combine)
{
  dim3 g(M/128, N/128, batch), bl(256);
  if (!TA && !TB)      mgemm_k<false,false><<<g,bl,0,st>>>(A,lda,sA,B,ldb,sB,C,ldc,sC,M,N,K,bias,scale,act,rowmul,combine);
  else if (!TA &&  TB) mgemm_k<false,true ><<<g,bl,0,st>>>(A,lda,sA,B,ldb,sB,C,ldc,sC,M,N,K,bias,scale,act,rowmul,combine);
  else                 mgemm_k<true ,false><<<g,bl,0,st>>>(A,lda,sA,B,ldb,sB,C,ldc,sC,M,N,K,bias,scale,act,rowmul,combine);
}

static void gemm_thin(hipStream_t st,
                      const float* A, int lda, const float* B, int ldb,
                      float* C, int ldc, int M, int N, int K,
                      const float* bias, float scale, int act,
                      const float* rowmul, int combine, float* part)
{
  const int S = 8;
  int chunk = ((K/S + 15)/16)*16; if (chunk < 16) chunk = 16;
  dim3 g((M+15)/16, (N+63)/64, S);
  gemm_part_k<<<g,256,0,st>>>(A,lda,B,ldb,part,M,N,K,chunk);
  i64 t = (i64)M*N;
  gemm_reduce_k<<<(int)((t+255)/256),256,0,st>>>(part,C,ldc,M,N,S,bias,scale,act,rowmul,combine);
}

extern "C" void kernel_launch(void* const* d_in, const int* in_sizes, int n_in,
                              void* d_out, int out_size, void* d_ws, size_t ws_size,
                              hipStream_t stream)
{
  const float* IN[64];
  for (int i=0;i<n_in && i<64;i++) IN[i] = (const float*)d_in[i];

  const float* single_act = IN[0];
  const float* pair_act   = IN[1];
  const float* sm         = IN[2];
  const float* pm         = IN[3];
  const float* opm_ln     = IN[4];
  const float* opm_lr_w   = IN[5];
  const float* opm_lr_b   = IN[6];
  const float* opm_out_w  = IN[7];
  const float* opm_out_b  = IN[8];
  const float* ra_ln      = IN[9];
  const float* ra_pair_ln = IN[10];
  const float* ra_feat_w  = IN[11];
  const float* ra_qkv_w   = IN[12];
  const float* ra_gate_w  = IN[13];
  const float* ra_gate_b  = IN[14];
  const float* ra_o_w     = IN[15];
  const float* ra_o_b     = IN[16];
  const float* st_ln      = IN[17];
  const float* st_w1      = IN[18];
  const float* st_b1      = IN[19];
  const float* st_w2      = IN[20];
  const float* st_b2      = IN[21];
  const float* pt_ln      = IN[56];
  const float* pt_w1      = IN[57];
  const float* pt_b1      = IN[58];
  const float* pt_w2      = IN[59];
  const float* pt_b2      = IN[60];

  float* sa = (float*)d_out;           // [256,384]
  float* pa = (float*)d_out + 98304;   // [256,256,128]

  float* W  = (float*)d_ws;
  float* B0 = W;
  float* B1 = W + 8388608L;
  float* B2 = W + 16777216L;
  float* B3 = W + 25165824L;
  float* SMA = W + 33554432L;
  float* xs   = SMA;
  float* qb   = SMA +  98304;
  float* kb   = SMA + 196608;
  float* vb   = SMA + 294912;
  float* wab  = SMA + 393216;
  float* hst  = SMA + 491520;   // 393216
  float* nbra = SMA + 884736;   // 524288 (reused as nbT in tri-attn phase)
  float* lbuf = SMA + 1409024;  // 8192
  float* rbuf = SMA + 1417216;  // 8192
  float* Wd   = SMA + 1425408;  // 1048576
  float* nbt  = SMA + 2473984;  // 262144

  // init outputs with residual bases
  copy_k<<<384, 256, 0, stream>>>(sa, single_act, 98304L);
  copy_k<<<32768, 256, 0, stream>>>(pa, pair_act, 8388608L);

  // ---- 1) OPM -> pair residual ----
  ln_k<<<256,128,0,stream>>>(single_act, xs, opm_ln, 384);
  gemm_thin(stream, xs,384, opm_lr_w,32,       lbuf,32, 256,32,384, opm_lr_b,    1.f,0, sm,0, B1);
  gemm_thin(stream, xs,384, opm_lr_w+12288,32, rbuf,32, 256,32,384, opm_lr_b+32, 1.f,0, sm,0, B1);
  opm_wd_k<<<dim3(256,32),128,0,stream>>>(rbuf, opm_out_w, Wd);
  opm_final_k<<<dim3(256,16),128,0,stream>>>(lbuf, Wd, opm_out_b, sm, pa);

  // ---- 2) row attention with pair bias ----
  ln_k<<<256,128,0,stream>>>(sa, xs, ra_ln, 384);
  ln_k<<<65536,128,0,stream>>>(pa, B0, ra_pair_ln, 128);
  gemm(stream,false,false, B0,128,0, ra_feat_w,8,0, nbra,8,0, 65536,8,128,1, nullptr,1.f,0,nullptr,0);
  const float qs_ra = 0.14433756729740643f; // 1/sqrt(48)
  gemm_thin(stream, xs,384, ra_qkv_w,384,        qb,384, 256,384,384, nullptr,qs_ra,0,nullptr,0, B1);
  gemm_thin(stream, xs,384, ra_qkv_w+147456,384, kb,384, 256,384,384, nullptr,1.f,0,nullptr,0, B1);
  gemm_thin(stream, xs,384, ra_qkv_w+294912,384, vb,384, 256,384,384, nullptr,1.f,0,nullptr,0, B1);
  ra_attn_k<<<dim3(256,8),256,0,stream>>>(qb, kb, vb, nbra, sm, wab);
  gemm_thin(stream, xs,384,  ra_gate_w,384, wab,384, 256,384,384, ra_gate_b,1.f,2,nullptr,2, B1);
  gemm_thin(stream, wab,384, ra_o_w,384,    sa,384,  256,384,384, ra_o_b,   1.f,0,nullptr,1, B1);

  // ---- 3) single transition ----
  ln_k<<<256,128,0,stream>>>(sa, xs, st_ln, 384);
  gemm_thin(stream, xs,384,   st_w1,1536, hst,1536, 256,1536,384, st_b1,1.f,1,nullptr,0, B1);
  gemm_thin(stream, hst,1536, st_w2,384,  sa,384,   256,384,1536, st_b2,1.f,0,nullptr,1, B1);

  // ---- 4/5) triangle multiplications ----
  auto tri_mult = [&](int base, bool outgoing){
    const float* ln_w = IN[base+0];
    const float* lr_w = IN[base+1];
    const float* lr_b = IN[base+2];
    const float* gw   = IN[base+3];
    const float* gb   = IN[base+4];
    const float* cln  = IN[base+5];
    const float* ow   = IN[base+6];
    const float* ob   = IN[base+7];
    const float* ogw  = IN[base+8];
    const float* ogb  = IN[base+9];
    ln_k<<<65536,128,0,stream>>>(pa, B0, ln_w, 128);
    // left = mask * (X@Wl+bl) * sigmoid(X@Wg+bg): fused dual-MFMA, then transpose+mask -> B1 (ch-major)
    mlrgate_k<<<512,256,0,stream>>>(B0, lr_w, lr_b, gw, gb, B3);
    tr_mask_k<<<dim3(2048,4),256,0,stream>>>(B3, pm, B1);
    // right -> B2 (ch-major)
    mlrgate_k<<<512,256,0,stream>>>(B0, lr_w+16384, lr_b+128, gw+16384, gb+128, B3);
    tr_mask_k<<<dim3(2048,4),256,0,stream>>>(B3, pm, B2);
    if (outgoing) // out[i,j,c] = sum_k L_c[i,k] * R_c[j,k]
      mgemm(stream,false,true, B1,256,65536, B2,256,65536, B3,256,65536, 256,256,256,128, nullptr,1.f,0,nullptr,0);
    else          // out[i,j,c] = sum_k R_c[k,i] * L_c[k,j]
      mgemm(stream,true,false, B2,256,65536, B1,256,65536, B3,256,65536, 256,256,256,128, nullptr,1.f,0,nullptr,0);
    chw2hwc_k<<<dim3(2048,4),256,0,stream>>>(B3, B1);
    ln_k<<<65536,128,0,stream>>>(B1, B3, cln, 128);
    mgemm(stream,false,false, B3,128,0, ow,128,0,  B1,128,0, 65536,128,128,1, ob,  1.f,0,nullptr,0);
    mgemm(stream,false,false, B0,128,0, ogw,128,0, B3,128,0, 65536,128,128,1, ogb, 1.f,2,nullptr,0);
    muladd_k<<<32768,256,0,stream>>>(pa, B1, B3, 8388608L);
  };
  tri_mult(22, true);   // tmo
  tri_mult(32, false);  // tmi

  // ---- 6/7) triangle attentions ----
  auto tri_attn = [&](int base, bool percol){
    const float* ln_w   = IN[base+0];
    const float* feat_w = IN[base+1];
    const float* qkv_w  = IN[base+2];
    const float* gw     = IN[base+3];
    const float* gb     = IN[base+4];
    const float* ow     = IN[base+5];
    const float* ob     = IN[base+6];
    const float* src = pa;
    if (percol){ transpose_pair_k<<<65536,128,0,stream>>>(B1, pa); src = B1; }
    ln_k<<<65536,128,0,stream>>>(src, B0, ln_w, 128);
    gemm(stream,false,false, B0,128,0, feat_w,4,0, nbt,4,0, 65536,4,128,1, nullptr,1.f,0,nullptr,0);
    nbT_k<<<256,256,0,stream>>>(nbt, nbra);  // nbT[h][k][q]
    const float qs = 0.17677669529663687f; // 1/sqrt(32)
    mgemm(stream,false,false, B0,128,0, qkv_w,128,0,       B1,128,0, 65536,128,128,1, nullptr,qs, 0,nullptr,0);
    mgemm(stream,false,false, B0,128,0, qkv_w+16384,128,0, B2,128,0, 65536,128,128,1, nullptr,1.f,0,nullptr,0);
    mgemm(stream,false,false, B0,128,0, qkv_w+32768,128,0, B3,128,0, 65536,128,128,1, nullptr,1.f,0,nullptr,0);
    ta_attn_k<<<dim3(256,4),256,0,stream>>>(B1, B2, B3, nbra, pm, percol?1:0, B1);
    mgemm(stream,false,false, B0,128,0, gw,128,0, B1,128,0, 65536,128,128,1, gb,1.f,2,nullptr,2); // wa *= sigmoid(gate)
    mgemm(stream,false,false, B1,128,0, ow,128,0, B2,128,0, 65536,128,128,1, ob,1.f,0,nullptr,0);
    resadd_k<<<65536,128,0,stream>>>(pa, B2, percol?1:0);
  };
  tri_attn(42, false);  // tas (per-row)
  tri_attn(49, true);   // tae (per-column)

  // ---- 8) pair transition ----
  ln_k<<<65536,128,0,stream>>>(pa, B0, pt_ln, 128);
  for (int half = 0; half < 2; half++){
    const float* xh = B0 + (i64)half*4194304;
    float* ph = pa + (i64)half*4194304;
    mgemm(stream,false,false, xh,128,0, pt_w1,512,0, B1,512,0, 32768,512,128,1, pt_b1,1.f,1,nullptr,0);
    mgemm(stream,false,false, B1,512,0, pt_w2,128,0, ph,128,0, 32768,128,512,1, pt_b2,1.f,0,nullptr,1);
  }
}

// Round 8
// 2090.838 us; speedup vs baseline: 3.3490x; 1.0130x over previous
//
#include <hip/hip_runtime.h>
#include <math.h>

typedef long long i64;
#define NN_ 65536L

typedef __attribute__((ext_vector_type(8))) short bf16x8;
typedef __attribute__((ext_vector_type(4))) float f32x4;

__device__ inline unsigned short f2bf(float f){
  unsigned int u = __float_as_uint(f);
  return (unsigned short)((u + 0x7FFFu + ((u>>16)&1u)) >> 16);
}

// ---------------- elementwise ----------------
__global__ __launch_bounds__(256) void copy_k(float* __restrict__ d, const float* __restrict__ s, long n){
  long i = (long)blockIdx.x*blockDim.x + threadIdx.x;
  if (i < n) d[i] = s[i];
}

// channel-major [128][65536] -> row-major [65536][128]
__global__ __launch_bounds__(256) void chw2hwc_k(const float* __restrict__ in, float* __restrict__ out){
  __shared__ float t[32][33];
  int r0 = blockIdx.x*32, c0 = blockIdx.y*32;
  int tx = threadIdx.x & 31, ty = threadIdx.x >> 5;
  for (int i = ty; i < 32; i += 8) t[i][tx] = in[(i64)(c0+i)*NN_ + r0 + tx];
  __syncthreads();
  for (int i = ty; i < 32; i += 8) out[(i64)(r0+i)*128 + c0 + tx] = t[tx][i];
}

// row-major [65536][128] -> ch-major [128][65536] with per-row mask
__global__ __launch_bounds__(256) void tr_mask_k(const float* __restrict__ in, const float* __restrict__ mask,
                                                 float* __restrict__ out){
  __shared__ float t[32][33];
  int r0 = blockIdx.x*32, c0 = blockIdx.y*32;
  int tx = threadIdx.x & 31, ty = threadIdx.x >> 5;
  for (int i = ty; i < 32; i += 8) t[i][tx] = in[(i64)(r0+i)*128 + c0 + tx];
  __syncthreads();
  for (int i = ty; i < 32; i += 8) out[(i64)(c0+i)*NN_ + r0 + tx] = t[tx][i] * mask[r0+tx];
}

// nb [q,k,h=4] -> nbT [h][k][q]
__global__ __launch_bounds__(256) void nbT_k(const float* __restrict__ in, float* __restrict__ out){
  int kk = blockIdx.x, qq = threadIdx.x;
  float4 vv = *(const float4*)(in + ((i64)qq*256 + kk)*4);
  out[0*65536 + kk*256 + qq] = vv.x;
  out[1*65536 + kk*256 + qq] = vv.y;
  out[2*65536 + kk*256 + qq] = vv.z;
  out[3*65536 + kk*256 + qq] = vv.w;
}

// ---------------- LayerNorm generic (rowwise, C arbitrary) ----------------
__global__ __launch_bounds__(128) void ln_k(const float* __restrict__ in, float* __restrict__ out,
                                            const float* __restrict__ w, int C){
  i64 row = blockIdx.x;
  const float* x = in + row*C;
  float* y = out + row*C;
  int tid = threadIdx.x;
  float s=0.f, s2=0.f;
  for (int c=tid;c<C;c+=128){ float v = x[c]; s += v; s2 += v*v; }
  __shared__ float rs[128], rq[128];
  rs[tid]=s; rq[tid]=s2; __syncthreads();
  for (int off=64;off>0;off>>=1){ if (tid<off){ rs[tid]+=rs[tid+off]; rq[tid]+=rq[tid+off]; } __syncthreads(); }
  float mu = rs[0]/C;
  float var = rq[0]/C - mu*mu;
  float inv = rsqrtf(var + 1e-5f);
  for (int c=tid;c<C;c+=128) y[c] = (x[c]-mu)*inv*w[c] + w[C+c];
}

// ---------------- LayerNorm C=128: one wave per row, shuffle-only reduction ----------------
// T=1: read row rt = transpose-pair index of row (fused pa transpose for per-column attention)
__global__ __launch_bounds__(256) void ln128_k(const float* __restrict__ in, float* __restrict__ out,
                                               const float* __restrict__ w, int T){
  int wv = threadIdx.x >> 6, lane = threadIdx.x & 63;
  i64 row = (i64)blockIdx.x*4 + wv;
  i64 rr = T ? (i64)((((int)row & 255) << 8) | ((int)row >> 8)) : row;
  float2 v = *(const float2*)(in + rr*128 + lane*2);
  float s = v.x + v.y, s2 = v.x*v.x + v.y*v.y;
  #pragma unroll
  for (int off=32; off; off>>=1){ s += __shfl_down(s, off); s2 += __shfl_down(s2, off); }
  s = __shfl(s, 0); s2 = __shfl(s2, 0);
  float mu = s*(1.f/128.f);
  float var = s2*(1.f/128.f) - mu*mu;
  float inv = rsqrtf(var + 1e-5f);
  float2 wl = *(const float2*)(w + lane*2);
  float2 wb = *(const float2*)(w + 128 + lane*2);
  float2 y; y.x = (v.x-mu)*inv*wl.x + wb.x; y.y = (v.y-mu)*inv*wl.y + wb.y;
  *(float2*)(out + row*128 + lane*2) = y;
}

// ---------------- bf16 MFMA GEMM: 128x128 tile, 256 thr (2x2 waves of 64x64) ----------------
// combine: 0 store, 1 +=, 2 *=, 3: C += aux*v, 4: C[transpose-pair(m)] += v (pair tensor only)
template<bool TA, bool TB>
__global__ __launch_bounds__(256) void mgemm_k(
    const float* __restrict__ A, int lda, i64 sA,
    const float* __restrict__ B, int ldb, i64 sB,
    float* __restrict__ C, int ldc, i64 sC,
    int M, int N, int K,
    const float* __restrict__ bias, float scale, int act,
    const float* __restrict__ rowmul, int combine, const float* __restrict__ aux)
{
  A += (i64)blockIdx.z * sA;
  B += (i64)blockIdx.z * sB;
  C += (i64)blockIdx.z * sC;
  int m0 = blockIdx.x * 128, n0 = blockIdx.y * 128;
  int tid = threadIdx.x;
  int wave = tid >> 6, lane = tid & 63;
  int quad = lane >> 4, mr = lane & 15;
  int wm = (wave >> 1) * 64, wn = (wave & 1) * 64;
  __shared__ unsigned short As[128][40];
  __shared__ unsigned short Bs[128][40];
  f32x4 acc[4][4];
  #pragma unroll
  for (int i=0;i<4;i++)
    #pragma unroll
    for (int j=0;j<4;j++) acc[i][j] = (f32x4){0.f,0.f,0.f,0.f};

  for (int k0 = 0; k0 < K; k0 += 32){
    if (!TA){
      #pragma unroll
      for (int it=0; it<4; it++){
        int lin = tid + it*256;
        int r = lin >> 3, c4 = (lin & 7) * 4;
        float4 g = *(const float4*)&A[(i64)(m0+r)*lda + k0 + c4];
        As[r][c4]   = f2bf(g.x); As[r][c4+1] = f2bf(g.y);
        As[r][c4+2] = f2bf(g.z); As[r][c4+3] = f2bf(g.w);
      }
    } else {
      #pragma unroll
      for (int it=0; it<4; it++){
        int lin = tid + it*256;
        int m = lin & 127, kg = (lin >> 7) * 4;
        float v0 = A[(i64)(k0+kg  )*lda + m0 + m];
        float v1 = A[(i64)(k0+kg+1)*lda + m0 + m];
        float v2 = A[(i64)(k0+kg+2)*lda + m0 + m];
        float v3 = A[(i64)(k0+kg+3)*lda + m0 + m];
        As[m][kg] = f2bf(v0); As[m][kg+1] = f2bf(v1);
        As[m][kg+2] = f2bf(v2); As[m][kg+3] = f2bf(v3);
      }
    }
    if (!TB){
      #pragma unroll
      for (int it=0; it<4; it++){
        int lin = tid + it*256;
        int n = lin & 127, kg = (lin >> 7) * 4;
        float v0 = B[(i64)(k0+kg  )*ldb + n0 + n];
        float v1 = B[(i64)(k0+kg+1)*ldb + n0 + n];
        float v2 = B[(i64)(k0+kg+2)*ldb + n0 + n];
        float v3 = B[(i64)(k0+kg+3)*ldb + n0 + n];
        Bs[n][kg] = f2bf(v0); Bs[n][kg+1] = f2bf(v1);
        Bs[n][kg+2] = f2bf(v2); Bs[n][kg+3] = f2bf(v3);
      }
    } else {
      #pragma unroll
      for (int it=0; it<4; it++){
        int lin = tid + it*256;
        int r = lin >> 3, c4 = (lin & 7) * 4;
        float4 g = *(const float4*)&B[(i64)(n0+r)*ldb + k0 + c4];
        Bs[r][c4]   = f2bf(g.x); Bs[r][c4+1] = f2bf(g.y);
        Bs[r][c4+2] = f2bf(g.z); Bs[r][c4+3] = f2bf(g.w);
      }
    }
    __syncthreads();
    bf16x8 af[4], bfr[4];
    #pragma unroll
    for (int i=0;i<4;i++) af[i]  = *(const bf16x8*)&As[wm + i*16 + mr][quad*8];
    #pragma unroll
    for (int j=0;j<4;j++) bfr[j] = *(const bf16x8*)&Bs[wn + j*16 + mr][quad*8];
    #pragma unroll
    for (int i=0;i<4;i++)
      #pragma unroll
      for (int j=0;j<4;j++)
        acc[i][j] = __builtin_amdgcn_mfma_f32_16x16x32_bf16(af[i], bfr[j], acc[i][j], 0, 0, 0);
    __syncthreads();
  }
  #pragma unroll
  for (int i=0;i<4;i++){
    #pragma unroll
    for (int r=0;r<4;r++){
      int m = m0 + wm + i*16 + quad*4 + r;
      float rm = rowmul ? rowmul[m] : 1.f;
      i64 mrow = (combine == 4) ? (i64)(((m & 255) << 8) | (m >> 8)) : (i64)m;
      #pragma unroll
      for (int j=0;j<4;j++){
        int n = n0 + wn + j*16 + mr;
        float v = acc[i][j][r] * scale;
        if (bias) v += bias[n];
        if (act == 1) v = fmaxf(v, 0.f);
        else if (act == 2) v = 1.f/(1.f + __expf(-v));
        v *= rm;
        i64 idx = mrow*ldc + n;
        if (combine == 0) C[idx] = v;
        else if (combine == 1 || combine == 4) C[idx] += v;
        else if (combine == 2) C[idx] *= v;
        else C[idx] += aux[(i64)m*ldc + n] * v;
      }
    }
  }
}

// ---------------- fused dual-MFMA lin*sigmoid(gate) for tri-mult (M=65536, N=128, K=128) ----------------
__global__ __launch_bounds__(256) void mlrgate_k(
    const float* __restrict__ X,
    const float* __restrict__ Wl, const float* __restrict__ bl,
    const float* __restrict__ Wg, const float* __restrict__ bg,
    float* __restrict__ Out)
{
  int m0 = blockIdx.x * 128;
  int tid = threadIdx.x;
  int wave = tid >> 6, lane = tid & 63;
  int quad = lane >> 4, mr = lane & 15;
  int wm = (wave >> 1) * 64, wn = (wave & 1) * 64;
  __shared__ unsigned short As[128][40], B1s[128][40], B2s[128][40];
  f32x4 acc1[4][4], acc2[4][4];
  #pragma unroll
  for (int i=0;i<4;i++)
    #pragma unroll
    for (int j=0;j<4;j++){ acc1[i][j] = (f32x4){0,0,0,0}; acc2[i][j] = (f32x4){0,0,0,0}; }

  for (int k0 = 0; k0 < 128; k0 += 32){
    #pragma unroll
    for (int it=0; it<4; it++){
      int lin = tid + it*256;
      int r = lin >> 3, c4 = (lin & 7) * 4;
      float4 g = *(const float4*)&X[(i64)(m0+r)*128 + k0 + c4];
      As[r][c4]   = f2bf(g.x); As[r][c4+1] = f2bf(g.y);
      As[r][c4+2] = f2bf(g.z); As[r][c4+3] = f2bf(g.w);
    }
    #pragma unroll
    for (int it=0; it<4; it++){
      int lin = tid + it*256;
      int n = lin & 127, kg = (lin >> 7) * 4;
      float a0 = Wl[(i64)(k0+kg  )*128 + n];
      float a1 = Wl[(i64)(k0+kg+1)*128 + n];
      float a2 = Wl[(i64)(k0+kg+2)*128 + n];
      float a3 = Wl[(i64)(k0+kg+3)*128 + n];
      B1s[n][kg] = f2bf(a0); B1s[n][kg+1] = f2bf(a1);
      B1s[n][kg+2] = f2bf(a2); B1s[n][kg+3] = f2bf(a3);
      float g0 = Wg[(i64)(k0+kg  )*128 + n];
      float g1 = Wg[(i64)(k0+kg+1)*128 + n];
      float g2 = Wg[(i64)(k0+kg+2)*128 + n];
      float g3 = Wg[(i64)(k0+kg+3)*128 + n];
      B2s[n][kg] = f2bf(g0); B2s[n][kg+1] = f2bf(g1);
      B2s[n][kg+2] = f2bf(g2); B2s[n][kg+3] = f2bf(g3);
    }
    __syncthreads();
    bf16x8 af[4], b1f[4], b2f[4];
    #pragma unroll
    for (int i=0;i<4;i++) af[i]  = *(const bf16x8*)&As[wm + i*16 + mr][quad*8];
    #pragma unroll
    for (int j=0;j<4;j++){
      b1f[j] = *(const bf16x8*)&B1s[wn + j*16 + mr][quad*8];
      b2f[j] = *(const bf16x8*)&B2s[wn + j*16 + mr][quad*8];
    }
    #pragma unroll
    for (int i=0;i<4;i++)
      #pragma unroll
      for (int j=0;j<4;j++){
        acc1[i][j] = __builtin_amdgcn_mfma_f32_16x16x32_bf16(af[i], b1f[j], acc1[i][j], 0, 0, 0);
        acc2[i][j] = __builtin_amdgcn_mfma_f32_16x16x32_bf16(af[i], b2f[j], acc2[i][j], 0, 0, 0);
      }
    __syncthreads();
  }
  #pragma unroll
  for (int i=0;i<4;i++){
    #pragma unroll
    for (int r=0;r<4;r++){
      int m = m0 + wm + i*16 + quad*4 + r;
      #pragma unroll
      for (int j=0;j<4;j++){
        int n = wn + j*16 + mr;
        float lv = acc1[i][j][r] + bl[n];
        float gv = acc2[i][j][r] + bg[n];
        Out[(i64)m*128 + n] = lv * (1.f/(1.f + __expf(-gv)));
      }
    }
  }
}

// ---------------- generic batched GEMM (fp32, 64x64 tile) ----------------
template<bool TA, bool TB>
__global__ __launch_bounds__(256) void gemm_k(
    const float* __restrict__ A, int lda, i64 sA,
    const float* __restrict__ B, int ldb, i64 sB,
    float* __restrict__ C, int ldc, i64 sC,
    int M, int N, int K,
    const float* __restrict__ bias, float scale, int act,
    const float* __restrict__ rowmul, int combine)
{
  A += (i64)blockIdx.z * sA;
  B += (i64)blockIdx.z * sB;
  C += (i64)blockIdx.z * sC;
  int m0 = blockIdx.x * 64, n0 = blockIdx.y * 64;
  int tid = threadIdx.x, tx = tid & 15, ty = tid >> 4;
  __shared__ float As[16][68], Bs[16][68];
  float acc[4][4] = {};
  for (int k0 = 0; k0 < K; k0 += 16){
    if (TA){
      for (int l = tid; l < 1024; l += 256){
        int kk = l >> 6, mi = l & 63; int m = m0 + mi;
        As[kk][mi] = (m < M) ? A[(i64)(k0+kk)*lda + m] : 0.f;
      }
    } else {
      for (int l = tid; l < 1024; l += 256){
        int mi = l >> 4, kk = l & 15; int m = m0 + mi;
        As[kk][mi] = (m < M) ? A[(i64)m*lda + k0 + kk] : 0.f;
      }
    }
    if (TB){
      for (int l = tid; l < 1024; l += 256){
        int ni = l >> 4, kk = l & 15; int n = n0 + ni;
        Bs[kk][ni] = (n < N) ? B[(i64)n*ldb + k0 + kk] : 0.f;
      }
    } else {
      for (int l = tid; l < 1024; l += 256){
        int kk = l >> 6, ni = l & 63; int n = n0 + ni;
        Bs[kk][ni] = (n < N) ? B[(i64)(k0+kk)*ldb + n] : 0.f;
      }
    }
    __syncthreads();
    #pragma unroll
    for (int kk = 0; kk < 16; ++kk){
      float4 av4 = *(const float4*)&As[kk][ty*4];
      float4 bv4 = *(const float4*)&Bs[kk][tx*4];
      float av[4] = {av4.x, av4.y, av4.z, av4.w};
      float bv[4] = {bv4.x, bv4.y, bv4.z, bv4.w};
      #pragma unroll
      for (int i=0;i<4;i++)
        #pragma unroll
        for (int j=0;j<4;j++) acc[i][j] = fmaf(av[i], bv[j], acc[i][j]);
    }
    __syncthreads();
  }
  #pragma unroll
  for (int i=0;i<4;i++){
    int m = m0 + ty*4 + i;
    if (m >= M) continue;
    float rm = rowmul ? rowmul[m] : 1.f;
    #pragma unroll
    for (int j=0;j<4;j++){
      int n = n0 + tx*4 + j;
      if (n >= N) continue;
      float v = acc[i][j] * scale;
      if (bias) v += bias[n];
      if (act == 1) v = fmaxf(v, 0.f);
      else if (act == 2) v = 1.f/(1.f + expf(-v));
      v *= rm;
      i64 idx = (i64)m*ldc + n;
      if (combine == 0) C[idx] = v;
      else if (combine == 1) C[idx] += v;
      else C[idx] *= v;
    }
  }
}

// ---------------- thin GEMM (small M): split-K two-phase ----------------
__global__ __launch_bounds__(256) void gemm_part_k(
    const float* __restrict__ A, int lda,
    const float* __restrict__ B, int ldb,
    float* __restrict__ Cp, int M, int N, int K, int chunk)
{
  int m0 = blockIdx.x*16, n0 = blockIdx.y*64, z = blockIdx.z;
  int kb = z*chunk, ke = min(K, kb+chunk);
  int tid = threadIdx.x;
  int mi = tid >> 4, ni4 = (tid & 15)*4;
  __shared__ float As[16][17], Bs[16][68];
  float acc[4] = {0.f,0.f,0.f,0.f};
  for (int k0 = kb; k0 < ke; k0 += 16){
    { int r = tid>>4, c = tid&15; int m = m0+r;
      As[c][r] = (m < M) ? A[(i64)m*lda + k0 + c] : 0.f; }
    for (int l = tid; l < 1024; l += 256){
      int kk = l>>6, nn = l&63; int n = n0+nn;
      Bs[kk][nn] = (n < N) ? B[(i64)(k0+kk)*ldb + n] : 0.f;
    }
    __syncthreads();
    #pragma unroll
    for (int kk=0;kk<16;kk++){
      float a = As[kk][mi];
      float4 b = *(const float4*)&Bs[kk][ni4];
      acc[0]=fmaf(a,b.x,acc[0]); acc[1]=fmaf(a,b.y,acc[1]);
      acc[2]=fmaf(a,b.z,acc[2]); acc[3]=fmaf(a,b.w,acc[3]);
    }
    __syncthreads();
  }
  int m = m0+mi, n = n0+ni4;
  if (m < M && n < N) *(float4*)&Cp[((i64)z*M + m)*N + n] = *(float4*)acc;
}

__global__ __launch_bounds__(256) void gemm_reduce_k(
    const float* __restrict__ Cp, float* __restrict__ C, int ldc,
    int M, int N, int S,
    const float* __restrict__ bias, float scale, int act,
    const float* __restrict__ rowmul, int combine)
{
  i64 idx = (i64)blockIdx.x*256 + threadIdx.x;
  if (idx >= (i64)M*N) return;
  int m = (int)(idx / N), n = (int)(idx % N);
  float s = 0.f;
  for (int z=0; z<S; z++) s += Cp[(i64)z*M*N + idx];
  float v = s*scale;
  if (bias) v += bias[n];
  if (act == 1) v = fmaxf(v, 0.f);
  else if (act == 2) v = 1.f/(1.f + expf(-v));
  if (rowmul) v *= rowmul[m];
  i64 o = (i64)m*ldc + n;
  if (combine == 0) C[o] = v;
  else if (combine == 1) C[o] += v;
  else C[o] *= v;
}

// ---------------- OPM ----------------
__global__ __launch_bounds__(128) void opm_wd_k(const float* __restrict__ right, const float* __restrict__ W,
                                                float* __restrict__ Wd){
  int d = blockIdx.x, c = blockIdx.y, f = threadIdx.x;
  float acc = 0.f;
  #pragma unroll
  for (int e=0;e<32;e++) acc = fmaf(right[d*32+e], W[((i64)c*32+e)*128 + f], acc);
  Wd[((i64)d*32+c)*128 + f] = acc;
}

__global__ __launch_bounds__(128) void opm_final_k(const float* __restrict__ left, const float* __restrict__ Wd,
                                                   const float* __restrict__ ob, const float* __restrict__ sm,
                                                   float* __restrict__ pa){
  int d = blockIdx.x, b0 = blockIdx.y*16, f = threadIdx.x;
  __shared__ float wd_s[32][128];
  __shared__ float l_s[16][32];
  for (int c=0;c<32;c++) wd_s[c][f] = Wd[((i64)d*32+c)*128 + f];
  for (int l = f; l < 512; l += 128){ int bi=l>>5, c=l&31; l_s[bi][c] = left[(b0+bi)*32 + c]; }
  __syncthreads();
  float md = sm[d], obf = ob[f];
  for (int bi=0;bi<16;bi++){
    float acc = 0.f;
    #pragma unroll
    for (int c=0;c<32;c++) acc = fmaf(l_s[bi][c], wd_s[c][f], acc);
    int b = b0+bi;
    pa[((i64)d*256 + b)*128 + f] += (acc + obf) / (1e-3f + md*sm[b]);
  }
}

// ---------------- row attention core ----------------
__global__ __launch_bounds__(256) void ra_attn_k(const float* __restrict__ q, const float* __restrict__ k,
                                                 const float* __restrict__ v, const float* __restrict__ nb,
                                                 const float* __restrict__ sm, float* __restrict__ wa){
  int qi = blockIdx.x, h = blockIdx.y, tid = threadIdx.x;
  __shared__ float qv[48];
  __shared__ float p[256];
  __shared__ float red[256];
  if (tid < 48) qv[tid] = q[(i64)qi*384 + h*48 + tid];
  __syncthreads();
  float acc = 0.f;
  const float* kr = k + (i64)tid*384 + h*48;
  #pragma unroll
  for (int c=0;c<48;c++) acc = fmaf(qv[c], kr[c], acc);
  acc += 1e9f*(sm[tid]-1.f) + nb[((i64)qi*256 + tid)*8 + h];
  red[tid] = acc; __syncthreads();
  for (int off=128;off>0;off>>=1){ if (tid<off) red[tid] = fmaxf(red[tid], red[tid+off]); __syncthreads(); }
  float mx = red[0]; __syncthreads();
  float e = expf(acc - mx);
  red[tid] = e; __syncthreads();
  for (int off=128;off>0;off>>=1){ if (tid<off) red[tid] += red[tid+off]; __syncthreads(); }
  p[tid] = e / red[0];
  __syncthreads();
  if (tid < 48){
    float a = 0.f;
    for (int kk=0;kk<256;kk++) a = fmaf(p[kk], v[(i64)kk*384 + h*48 + tid], a);
    wa[(i64)qi*384 + h*48 + tid] = a;
  }
}

// ---------------- triangle attention core v5: 16-row staging, 8-row compute groups ----------------
// 1 q-row/thread, 256 thr (4 waves). s[8] reuse keeps VGPR ~64; barriers halved vs v4.
__global__ __launch_bounds__(256) void ta_attn_k(
    const float* __restrict__ q, const float* __restrict__ k, const float* __restrict__ v,
    const float* __restrict__ nbT, const float* __restrict__ mask, int maskT,
    float* __restrict__ wa)
{
  int b = blockIdx.x, h = blockIdx.y, tid = threadIdx.x;
  const i64 headoff = ((i64)b*256)*128 + h*32;
  const float* qp = q + headoff;
  const float* kp = k + headoff;
  const float* vp = v + headoff;
  const float* nbh = nbT + (i64)h*65536;

  float Q[32];
  #pragma unroll
  for (int cc = 0; cc < 32; cc += 4){
    float4 a = *(const float4*)(qp + (i64)tid*128 + cc);
    Q[cc]=a.x; Q[cc+1]=a.y; Q[cc+2]=a.z; Q[cc+3]=a.w;
  }
  float acc[32];
  #pragma unroll
  for (int c = 0; c < 32; c++) acc[c]=0.f;
  float mx=-1e30f, lsum=0.f;

  __shared__ float Ks[16][32];
  __shared__ float Vs[16][32];
  int r = tid >> 4, c2 = (tid & 15)*2;

  for (int kc = 0; kc < 256; kc += 16){
    __syncthreads();
    *(float2*)&Ks[r][c2] = *(const float2*)(kp + (i64)(kc+r)*128 + c2);
    *(float2*)&Vs[r][c2] = *(const float2*)(vp + (i64)(kc+r)*128 + c2);
    __syncthreads();
    #pragma unroll
    for (int g = 0; g < 2; g++){
      float s[8];
      #pragma unroll
      for (int j = 0; j < 8; j++){
        int kl = g*8 + j;
        float d = 0.f;
        #pragma unroll
        for (int cc = 0; cc < 32; cc += 4){
          float4 kv = *(const float4*)&Ks[kl][cc];
          d = fmaf(Q[cc],kv.x,d); d = fmaf(Q[cc+1],kv.y,d);
          d = fmaf(Q[cc+2],kv.z,d); d = fmaf(Q[cc+3],kv.w,d);
        }
        int kk = kc + kl;
        float mv = maskT ? mask[(i64)kk*256 + b] : mask[(i64)b*256 + kk];
        s[j] = d + 1e9f*(mv - 1.f) + nbh[(i64)kk*256 + tid];
      }
      float nm = mx;
      #pragma unroll
      for (int j=0;j<8;j++) nm = fmaxf(nm, s[j]);
      float alpha = __expf(mx-nm);
      mx = nm; lsum *= alpha;
      #pragma unroll
      for (int cc=0;cc<32;cc++) acc[cc] *= alpha;
      #pragma unroll
      for (int j=0;j<8;j++){
        int kl = g*8 + j;
        float p = __expf(s[j]-mx);
        lsum += p;
        #pragma unroll
        for (int cc=0; cc<32; cc+=4){
          float4 vv = *(const float4*)&Vs[kl][cc];
          acc[cc]  += p*vv.x; acc[cc+1]+= p*vv.y; acc[cc+2]+= p*vv.z; acc[cc+3]+= p*vv.w;
        }
      }
    }
  }
  float inv = 1.f/lsum;
  float* w0 = wa + headoff + (i64)tid*128;
  #pragma unroll
  for (int cc=0; cc<32; cc+=4)
    *(float4*)(w0+cc) = make_float4(acc[cc]*inv, acc[cc+1]*inv, acc[cc+2]*inv, acc[cc+3]*inv);
}

// ---------------- host dispatch ----------------
static void gemm(hipStream_t st, bool TA, bool TB,
                 const float* A, int lda, i64 sA,
                 const float* B, int ldb, i64 sB,
                 float* C, int ldc, i64 sC,
                 int M, int N, int K, int batch,
                 const float* bias, float scale, int act,
                 const float* rowmul, int combine)
{
  dim3 g((M+63)/64, (N+63)/64, batch), bl(256);
  if (!TA && !TB)      gemm_k<false,false><<<g,bl,0,st>>>(A,lda,sA,B,ldb,sB,C,ldc,sC,M,N,K,bias,scale,act,rowmul,combine);
  else if (!TA &&  TB) gemm_k<false,true ><<<g,bl,0,st>>>(A,lda,sA,B,ldb,sB,C,ldc,sC,M,N,K,bias,scale,act,rowmul,combine);
  else                 gemm_k<true ,false><<<g,bl,0,st>>>(A,lda,sA,B,ldb,sB,C,ldc,sC,M,N,K,bias,scale,act,rowmul,combine);
}

static void mgemm(hipStream_t st, bool TA, bool TB,
                  const float* A, int lda, i64 sA,
                  const float* B, int ldb, i64 sB,
                  float* C, int ldc, i64 sC,
                  int M, int N, int K, int batch,
                  const float* bias, float scale, int act,
                  const float* rowmul, int combine, const float* aux = nullptr)
{
  dim3 g(M/128, N/128, batch), bl(256);
  if (!TA && !TB)      mgemm_k<false,false><<<g,bl,0,st>>>(A,lda,sA,B,ldb,sB,C,ldc,sC,M,N,K,bias,scale,act,rowmul,combine,aux);
  else if (!TA &&  TB) mgemm_k<false,true ><<<g,bl,0,st>>>(A,lda,sA,B,ldb,sB,C,ldc,sC,M,N,K,bias,scale,act,rowmul,combine,aux);
  else                 mgemm_k<true ,false><<<g,bl,0,st>>>(A,lda,sA,B,ldb,sB,C,ldc,sC,M,N,K,bias,scale,act,rowmul,combine,aux);
}

static void gemm_thin(hipStream_t st,
                      const float* A, int lda, const float* B, int ldb,
                      float* C, int ldc, int M, int N, int K,
                      const float* bias, float scale, int act,
                      const float* rowmul, int combine, float* part)
{
  const int S = 8;
  int chunk = ((K/S + 15)/16)*16; if (chunk < 16) chunk = 16;
  dim3 g((M+15)/16, (N+63)/64, S);
  gemm_part_k<<<g,256,0,st>>>(A,lda,B,ldb,part,M,N,K,chunk);
  i64 t = (i64)M*N;
  gemm_reduce_k<<<(int)((t+255)/256),256,0,st>>>(part,C,ldc,M,N,S,bias,scale,act,rowmul,combine);
}

extern "C" void kernel_launch(void* const* d_in, const int* in_sizes, int n_in,
                              void* d_out, int out_size, void* d_ws, size_t ws_size,
                              hipStream_t stream)
{
  const float* IN[64];
  for (int i=0;i<n_in && i<64;i++) IN[i] = (const float*)d_in[i];

  const float* single_act = IN[0];
  const float* pair_act   = IN[1];
  const float* sm         = IN[2];
  const float* pm         = IN[3];
  const float* opm_ln     = IN[4];
  const float* opm_lr_w   = IN[5];
  const float* opm_lr_b   = IN[6];
  const float* opm_out_w  = IN[7];
  const float* opm_out_b  = IN[8];
  const float* ra_ln      = IN[9];
  const float* ra_pair_ln = IN[10];
  const float* ra_feat_w  = IN[11];
  const float* ra_qkv_w   = IN[12];
  const float* ra_gate_w  = IN[13];
  const float* ra_gate_b  = IN[14];
  const float* ra_o_w     = IN[15];
  const float* ra_o_b     = IN[16];
  const float* st_ln      = IN[17];
  const float* st_w1      = IN[18];
  const float* st_b1      = IN[19];
  const float* st_w2      = IN[20];
  const float* st_b2      = IN[21];
  const float* pt_ln      = IN[56];
  const float* pt_w1      = IN[57];
  const float* pt_b1      = IN[58];
  const float* pt_w2      = IN[59];
  const float* pt_b2      = IN[60];

  float* sa = (float*)d_out;           // [256,384]
  float* pa = (float*)d_out + 98304;   // [256,256,128]

  float* W  = (float*)d_ws;
  float* B0 = W;
  float* B1 = W + 8388608L;
  float* B2 = W + 16777216L;
  float* B3 = W + 25165824L;
  float* SMA = W + 33554432L;
  float* xs   = SMA;
  float* qb   = SMA +  98304;
  float* kb   = SMA + 196608;
  float* vb   = SMA + 294912;
  float* wab  = SMA + 393216;
  float* hst  = SMA + 491520;   // 393216
  float* nbra = SMA + 884736;   // 524288 (reused as nbT in tri-attn phase)
  float* lbuf = SMA + 1409024;  // 8192
  float* rbuf = SMA + 1417216;  // 8192
  float* Wd   = SMA + 1425408;  // 1048576
  float* nbt  = SMA + 2473984;  // 262144

  // init outputs with residual bases
  copy_k<<<384, 256, 0, stream>>>(sa, single_act, 98304L);
  copy_k<<<32768, 256, 0, stream>>>(pa, pair_act, 8388608L);

  // ---- 1) OPM -> pair residual ----
  ln_k<<<256,128,0,stream>>>(single_act, xs, opm_ln, 384);
  gemm_thin(stream, xs,384, opm_lr_w,32,       lbuf,32, 256,32,384, opm_lr_b,    1.f,0, sm,0, B1);
  gemm_thin(stream, xs,384, opm_lr_w+12288,32, rbuf,32, 256,32,384, opm_lr_b+32, 1.f,0, sm,0, B1);
  opm_wd_k<<<dim3(256,32),128,0,stream>>>(rbuf, opm_out_w, Wd);
  opm_final_k<<<dim3(256,16),128,0,stream>>>(lbuf, Wd, opm_out_b, sm, pa);

  // ---- 2) row attention with pair bias ----
  ln_k<<<256,128,0,stream>>>(sa, xs, ra_ln, 384);
  ln128_k<<<16384,256,0,stream>>>(pa, B0, ra_pair_ln, 0);
  gemm(stream,false,false, B0,128,0, ra_feat_w,8,0, nbra,8,0, 65536,8,128,1, nullptr,1.f,0,nullptr,0);
  const float qs_ra = 0.14433756729740643f; // 1/sqrt(48)
  gemm_thin(stream, xs,384, ra_qkv_w,384,        qb,384, 256,384,384, nullptr,qs_ra,0,nullptr,0, B1);
  gemm_thin(stream, xs,384, ra_qkv_w+147456,384, kb,384, 256,384,384, nullptr,1.f,0,nullptr,0, B1);
  gemm_thin(stream, xs,384, ra_qkv_w+294912,384, vb,384, 256,384,384, nullptr,1.f,0,nullptr,0, B1);
  ra_attn_k<<<dim3(256,8),256,0,stream>>>(qb, kb, vb, nbra, sm, wab);
  gemm_thin(stream, xs,384,  ra_gate_w,384, wab,384, 256,384,384, ra_gate_b,1.f,2,nullptr,2, B1);
  gemm_thin(stream, wab,384, ra_o_w,384,    sa,384,  256,384,384, ra_o_b,   1.f,0,nullptr,1, B1);

  // ---- 3) single transition ----
  ln_k<<<256,128,0,stream>>>(sa, xs, st_ln, 384);
  gemm_thin(stream, xs,384,   st_w1,1536, hst,1536, 256,1536,384, st_b1,1.f,1,nullptr,0, B1);
  gemm_thin(stream, hst,1536, st_w2,384,  sa,384,   256,384,1536, st_b2,1.f,0,nullptr,1, B1);

  // ---- 4/5) triangle multiplications ----
  auto tri_mult = [&](int base, bool outgoing){
    const float* ln_w = IN[base+0];
    const float* lr_w = IN[base+1];
    const float* lr_b = IN[base+2];
    const float* gw   = IN[base+3];
    const float* gb   = IN[base+4];
    const float* cln  = IN[base+5];
    const float* ow   = IN[base+6];
    const float* ob   = IN[base+7];
    const float* ogw  = IN[base+8];
    const float* ogb  = IN[base+9];
    ln128_k<<<16384,256,0,stream>>>(pa, B0, ln_w, 0);
    // left = mask * (X@Wl+bl) * sigmoid(X@Wg+bg): fused dual-MFMA, then transpose+mask -> B1 (ch-major)
    mlrgate_k<<<512,256,0,stream>>>(B0, lr_w, lr_b, gw, gb, B3);
    tr_mask_k<<<dim3(2048,4),256,0,stream>>>(B3, pm, B1);
    // right -> B2 (ch-major)
    mlrgate_k<<<512,256,0,stream>>>(B0, lr_w+16384, lr_b+128, gw+16384, gb+128, B3);
    tr_mask_k<<<dim3(2048,4),256,0,stream>>>(B3, pm, B2);
    if (outgoing) // out[i,j,c] = sum_k L_c[i,k] * R_c[j,k]
      mgemm(stream,false,true, B1,256,65536, B2,256,65536, B3,256,65536, 256,256,256,128, nullptr,1.f,0,nullptr,0);
    else          // out[i,j,c] = sum_k R_c[k,i] * L_c[k,j]
      mgemm(stream,true,false, B2,256,65536, B1,256,65536, B3,256,65536, 256,256,256,128, nullptr,1.f,0,nullptr,0);
    chw2hwc_k<<<dim3(2048,4),256,0,stream>>>(B3, B1);
    ln128_k<<<16384,256,0,stream>>>(B1, B3, cln, 0);
    mgemm(stream,false,false, B3,128,0, ow,128,0,  B1,128,0, 65536,128,128,1, ob,  1.f,0,nullptr,0);
    // fused: pa += B1 * sigmoid(B0@ogw + ogb)
    mgemm(stream,false,false, B0,128,0, ogw,128,0, pa,128,0, 65536,128,128,1, ogb, 1.f,2,nullptr,3, B1);
  };
  tri_mult(22, true);   // tmo
  tri_mult(32, false);  // tmi

  // ---- 6/7) triangle attentions ----
  auto tri_attn = [&](int base, bool percol){
    const float* ln_w   = IN[base+0];
    const float* feat_w = IN[base+1];
    const float* qkv_w  = IN[base+2];
    const float* gw     = IN[base+3];
    const float* gb     = IN[base+4];
    const float* ow     = IN[base+5];
    const float* ob     = IN[base+6];
    // LN with fused pair-transpose read for per-column attention
    ln128_k<<<16384,256,0,stream>>>(pa, B0, ln_w, percol?1:0);
    gemm(stream,false,false, B0,128,0, feat_w,4,0, nbt,4,0, 65536,4,128,1, nullptr,1.f,0,nullptr,0);
    nbT_k<<<256,256,0,stream>>>(nbt, nbra);  // nbT[h][k][q]
    const float qs = 0.17677669529663687f; // 1/sqrt(32)
    mgemm(stream,false,false, B0,128,0, qkv_w,128,0,       B1,128,0, 65536,128,128,1, nullptr,qs, 0,nullptr,0);
    mgemm(stream,false,false, B0,128,0, qkv_w+16384,128,0, B2,128,0, 65536,128,128,1, nullptr,1.f,0,nullptr,0);
    mgemm(stream,false,false, B0,128,0, qkv_w+32768,128,0, B3,128,0, 65536,128,128,1, nullptr,1.f,0,nullptr,0);
    ta_attn_k<<<dim3(256,4),256,0,stream>>>(B1, B2, B3, nbra, pm, percol?1:0, B1);
    mgemm(stream,false,false, B0,128,0, gw,128,0, B1,128,0, 65536,128,128,1, gb,1.f,2,nullptr,2); // wa *= sigmoid(gate)
    // out-projection fused with residual add (4 = transpose-pair write for per-column)
    mgemm(stream,false,false, B1,128,0, ow,128,0, pa,128,0, 65536,128,128,1, ob,1.f,0,nullptr, percol?4:1);
  };
  tri_attn(42, false);  // tas (per-row)
  tri_attn(49, true);   // tae (per-column)

  // ---- 8) pair transition ----
  ln128_k<<<16384,256,0,stream>>>(pa, B0, pt_ln, 0);
  for (int half = 0; half < 2; half++){
    const float* xh = B0 + (i64)half*4194304;
    float* ph = pa + (i64)half*4194304;
    mgemm(stream,false,false, xh,128,0, pt_w1,512,0, B1,512,0, 32768,512,128,1, pt_b1,1.f,1,nullptr,0);
    mgemm(stream,false,false, B1,512,0, pt_w2,128,0, ph,128,0, 32768,128,512,1, pt_b2,1.f,0,nullptr,1);
  }
}

// Round 9
// 2017.274 us; speedup vs baseline: 3.4711x; 1.0365x over previous
//
#include <hip/hip_runtime.h>
#include <math.h>

typedef long long i64;
#define NN_ 65536L

typedef __attribute__((ext_vector_type(8))) short bf16x8;
typedef __attribute__((ext_vector_type(4))) float f32x4;

__device__ inline unsigned short f2bf(float f){
  unsigned int u = __float_as_uint(f);
  return (unsigned short)((u + 0x7FFFu + ((u>>16)&1u)) >> 16);
}

// ---------------- elementwise ----------------
__global__ __launch_bounds__(256) void copy_k(float* __restrict__ d, const float* __restrict__ s, long n){
  long i = (long)blockIdx.x*blockDim.x + threadIdx.x;
  if (i < n) d[i] = s[i];
}

// channel-major [128][65536] -> row-major [65536][128]
__global__ __launch_bounds__(256) void chw2hwc_k(const float* __restrict__ in, float* __restrict__ out){
  __shared__ float t[32][33];
  int r0 = blockIdx.x*32, c0 = blockIdx.y*32;
  int tx = threadIdx.x & 31, ty = threadIdx.x >> 5;
  for (int i = ty; i < 32; i += 8) t[i][tx] = in[(i64)(c0+i)*NN_ + r0 + tx];
  __syncthreads();
  for (int i = ty; i < 32; i += 8) out[(i64)(r0+i)*128 + c0 + tx] = t[tx][i];
}

// row-major [65536][128] -> ch-major [128][65536] with per-row mask
__global__ __launch_bounds__(256) void tr_mask_k(const float* __restrict__ in, const float* __restrict__ mask,
                                                 float* __restrict__ out){
  __shared__ float t[32][33];
  int r0 = blockIdx.x*32, c0 = blockIdx.y*32;
  int tx = threadIdx.x & 31, ty = threadIdx.x >> 5;
  for (int i = ty; i < 32; i += 8) t[i][tx] = in[(i64)(r0+i)*128 + c0 + tx];
  __syncthreads();
  for (int i = ty; i < 32; i += 8) out[(i64)(c0+i)*NN_ + r0 + tx] = t[tx][i] * mask[r0+tx];
}

// nb [q,k,h=4] -> nbT [h][k][q]
__global__ __launch_bounds__(256) void nbT_k(const float* __restrict__ in, float* __restrict__ out){
  int kk = blockIdx.x, qq = threadIdx.x;
  float4 vv = *(const float4*)(in + ((i64)qq*256 + kk)*4);
  out[0*65536 + kk*256 + qq] = vv.x;
  out[1*65536 + kk*256 + qq] = vv.y;
  out[2*65536 + kk*256 + qq] = vv.z;
  out[3*65536 + kk*256 + qq] = vv.w;
}

// ---------------- LayerNorm generic (rowwise, C arbitrary) ----------------
__global__ __launch_bounds__(128) void ln_k(const float* __restrict__ in, float* __restrict__ out,
                                            const float* __restrict__ w, int C){
  i64 row = blockIdx.x;
  const float* x = in + row*C;
  float* y = out + row*C;
  int tid = threadIdx.x;
  float s=0.f, s2=0.f;
  for (int c=tid;c<C;c+=128){ float v = x[c]; s += v; s2 += v*v; }
  __shared__ float rs[128], rq[128];
  rs[tid]=s; rq[tid]=s2; __syncthreads();
  for (int off=64;off>0;off>>=1){ if (tid<off){ rs[tid]+=rs[tid+off]; rq[tid]+=rq[tid+off]; } __syncthreads(); }
  float mu = rs[0]/C;
  float var = rq[0]/C - mu*mu;
  float inv = rsqrtf(var + 1e-5f);
  for (int c=tid;c<C;c+=128) y[c] = (x[c]-mu)*inv*w[c] + w[C+c];
}

// ---------------- LayerNorm C=128: one wave per row, shuffle-only reduction ----------------
// T=1: read row rt = transpose-pair index of row (fused pa transpose for per-column attention)
__global__ __launch_bounds__(256) void ln128_k(const float* __restrict__ in, float* __restrict__ out,
                                               const float* __restrict__ w, int T){
  int wv = threadIdx.x >> 6, lane = threadIdx.x & 63;
  i64 row = (i64)blockIdx.x*4 + wv;
  i64 rr = T ? (i64)((((int)row & 255) << 8) | ((int)row >> 8)) : row;
  float2 v = *(const float2*)(in + rr*128 + lane*2);
  float s = v.x + v.y, s2 = v.x*v.x + v.y*v.y;
  #pragma unroll
  for (int off=32; off; off>>=1){ s += __shfl_down(s, off); s2 += __shfl_down(s2, off); }
  s = __shfl(s, 0); s2 = __shfl(s2, 0);
  float mu = s*(1.f/128.f);
  float var = s2*(1.f/128.f) - mu*mu;
  float inv = rsqrtf(var + 1e-5f);
  float2 wl = *(const float2*)(w + lane*2);
  float2 wb = *(const float2*)(w + 128 + lane*2);
  float2 y; y.x = (v.x-mu)*inv*wl.x + wb.x; y.y = (v.y-mu)*inv*wl.y + wb.y;
  *(float2*)(out + row*128 + lane*2) = y;
}

// ---------------- bf16 MFMA GEMM: 128x128 tile, 256 thr (2x2 waves of 64x64) ----------------
// combine: 0 store, 1 +=, 2 *=, 3: C += aux*v, 4: C[transpose-pair(m)] += v (pair tensor only)
template<bool TA, bool TB>
__global__ __launch_bounds__(256) void mgemm_k(
    const float* __restrict__ A, int lda, i64 sA,
    const float* __restrict__ B, int ldb, i64 sB,
    float* __restrict__ C, int ldc, i64 sC,
    int M, int N, int K,
    const float* __restrict__ bias, float scale, int act,
    const float* __restrict__ rowmul, int combine, const float* __restrict__ aux)
{
  A += (i64)blockIdx.z * sA;
  B += (i64)blockIdx.z * sB;
  C += (i64)blockIdx.z * sC;
  int m0 = blockIdx.x * 128, n0 = blockIdx.y * 128;
  int tid = threadIdx.x;
  int wave = tid >> 6, lane = tid & 63;
  int quad = lane >> 4, mr = lane & 15;
  int wm = (wave >> 1) * 64, wn = (wave & 1) * 64;
  __shared__ unsigned short As[128][40];
  __shared__ unsigned short Bs[128][40];
  f32x4 acc[4][4];
  #pragma unroll
  for (int i=0;i<4;i++)
    #pragma unroll
    for (int j=0;j<4;j++) acc[i][j] = (f32x4){0.f,0.f,0.f,0.f};

  for (int k0 = 0; k0 < K; k0 += 32){
    if (!TA){
      #pragma unroll
      for (int it=0; it<4; it++){
        int lin = tid + it*256;
        int r = lin >> 3, c4 = (lin & 7) * 4;
        float4 g = *(const float4*)&A[(i64)(m0+r)*lda + k0 + c4];
        As[r][c4]   = f2bf(g.x); As[r][c4+1] = f2bf(g.y);
        As[r][c4+2] = f2bf(g.z); As[r][c4+3] = f2bf(g.w);
      }
    } else {
      #pragma unroll
      for (int it=0; it<4; it++){
        int lin = tid + it*256;
        int m = lin & 127, kg = (lin >> 7) * 4;
        float v0 = A[(i64)(k0+kg  )*lda + m0 + m];
        float v1 = A[(i64)(k0+kg+1)*lda + m0 + m];
        float v2 = A[(i64)(k0+kg+2)*lda + m0 + m];
        float v3 = A[(i64)(k0+kg+3)*lda + m0 + m];
        As[m][kg] = f2bf(v0); As[m][kg+1] = f2bf(v1);
        As[m][kg+2] = f2bf(v2); As[m][kg+3] = f2bf(v3);
      }
    }
    if (!TB){
      #pragma unroll
      for (int it=0; it<4; it++){
        int lin = tid + it*256;
        int n = lin & 127, kg = (lin >> 7) * 4;
        float v0 = B[(i64)(k0+kg  )*ldb + n0 + n];
        float v1 = B[(i64)(k0+kg+1)*ldb + n0 + n];
        float v2 = B[(i64)(k0+kg+2)*ldb + n0 + n];
        float v3 = B[(i64)(k0+kg+3)*ldb + n0 + n];
        Bs[n][kg] = f2bf(v0); Bs[n][kg+1] = f2bf(v1);
        Bs[n][kg+2] = f2bf(v2); Bs[n][kg+3] = f2bf(v3);
      }
    } else {
      #pragma unroll
      for (int it=0; it<4; it++){
        int lin = tid + it*256;
        int r = lin >> 3, c4 = (lin & 7) * 4;
        float4 g = *(const float4*)&B[(i64)(n0+r)*ldb + k0 + c4];
        Bs[r][c4]   = f2bf(g.x); Bs[r][c4+1] = f2bf(g.y);
        Bs[r][c4+2] = f2bf(g.z); Bs[r][c4+3] = f2bf(g.w);
      }
    }
    __syncthreads();
    bf16x8 af[4], bfr[4];
    #pragma unroll
    for (int i=0;i<4;i++) af[i]  = *(const bf16x8*)&As[wm + i*16 + mr][quad*8];
    #pragma unroll
    for (int j=0;j<4;j++) bfr[j] = *(const bf16x8*)&Bs[wn + j*16 + mr][quad*8];
    #pragma unroll
    for (int i=0;i<4;i++)
      #pragma unroll
      for (int j=0;j<4;j++)
        acc[i][j] = __builtin_amdgcn_mfma_f32_16x16x32_bf16(af[i], bfr[j], acc[i][j], 0, 0, 0);
    __syncthreads();
  }
  #pragma unroll
  for (int i=0;i<4;i++){
    #pragma unroll
    for (int r=0;r<4;r++){
      int m = m0 + wm + i*16 + quad*4 + r;
      float rm = rowmul ? rowmul[m] : 1.f;
      i64 mrow = (combine == 4) ? (i64)(((m & 255) << 8) | (m >> 8)) : (i64)m;
      #pragma unroll
      for (int j=0;j<4;j++){
        int n = n0 + wn + j*16 + mr;
        float v = acc[i][j][r] * scale;
        if (bias) v += bias[n];
        if (act == 1) v = fmaxf(v, 0.f);
        else if (act == 2) v = 1.f/(1.f + __expf(-v));
        v *= rm;
        i64 idx = mrow*ldc + n;
        if (combine == 0) C[idx] = v;
        else if (combine == 1 || combine == 4) C[idx] += v;
        else if (combine == 2) C[idx] *= v;
        else C[idx] += aux[(i64)m*ldc + n] * v;
      }
    }
  }
}

// ---------------- fused dual-MFMA lin*sigmoid(gate) for tri-mult (M=65536, N=128, K=128) ----------------
__global__ __launch_bounds__(256) void mlrgate_k(
    const float* __restrict__ X,
    const float* __restrict__ Wl, const float* __restrict__ bl,
    const float* __restrict__ Wg, const float* __restrict__ bg,
    float* __restrict__ Out)
{
  int m0 = blockIdx.x * 128;
  int tid = threadIdx.x;
  int wave = tid >> 6, lane = tid & 63;
  int quad = lane >> 4, mr = lane & 15;
  int wm = (wave >> 1) * 64, wn = (wave & 1) * 64;
  __shared__ unsigned short As[128][40], B1s[128][40], B2s[128][40];
  f32x4 acc1[4][4], acc2[4][4];
  #pragma unroll
  for (int i=0;i<4;i++)
    #pragma unroll
    for (int j=0;j<4;j++){ acc1[i][j] = (f32x4){0,0,0,0}; acc2[i][j] = (f32x4){0,0,0,0}; }

  for (int k0 = 0; k0 < 128; k0 += 32){
    #pragma unroll
    for (int it=0; it<4; it++){
      int lin = tid + it*256;
      int r = lin >> 3, c4 = (lin & 7) * 4;
      float4 g = *(const float4*)&X[(i64)(m0+r)*128 + k0 + c4];
      As[r][c4]   = f2bf(g.x); As[r][c4+1] = f2bf(g.y);
      As[r][c4+2] = f2bf(g.z); As[r][c4+3] = f2bf(g.w);
    }
    #pragma unroll
    for (int it=0; it<4; it++){
      int lin = tid + it*256;
      int n = lin & 127, kg = (lin >> 7) * 4;
      float a0 = Wl[(i64)(k0+kg  )*128 + n];
      float a1 = Wl[(i64)(k0+kg+1)*128 + n];
      float a2 = Wl[(i64)(k0+kg+2)*128 + n];
      float a3 = Wl[(i64)(k0+kg+3)*128 + n];
      B1s[n][kg] = f2bf(a0); B1s[n][kg+1] = f2bf(a1);
      B1s[n][kg+2] = f2bf(a2); B1s[n][kg+3] = f2bf(a3);
      float g0 = Wg[(i64)(k0+kg  )*128 + n];
      float g1 = Wg[(i64)(k0+kg+1)*128 + n];
      float g2 = Wg[(i64)(k0+kg+2)*128 + n];
      float g3 = Wg[(i64)(k0+kg+3)*128 + n];
      B2s[n][kg] = f2bf(g0); B2s[n][kg+1] = f2bf(g1);
      B2s[n][kg+2] = f2bf(g2); B2s[n][kg+3] = f2bf(g3);
    }
    __syncthreads();
    bf16x8 af[4], b1f[4], b2f[4];
    #pragma unroll
    for (int i=0;i<4;i++) af[i]  = *(const bf16x8*)&As[wm + i*16 + mr][quad*8];
    #pragma unroll
    for (int j=0;j<4;j++){
      b1f[j] = *(const bf16x8*)&B1s[wn + j*16 + mr][quad*8];
      b2f[j] = *(const bf16x8*)&B2s[wn + j*16 + mr][quad*8];
    }
    #pragma unroll
    for (int i=0;i<4;i++)
      #pragma unroll
      for (int j=0;j<4;j++){
        acc1[i][j] = __builtin_amdgcn_mfma_f32_16x16x32_bf16(af[i], b1f[j], acc1[i][j], 0, 0, 0);
        acc2[i][j] = __builtin_amdgcn_mfma_f32_16x16x32_bf16(af[i], b2f[j], acc2[i][j], 0, 0, 0);
      }
    __syncthreads();
  }
  #pragma unroll
  for (int i=0;i<4;i++){
    #pragma unroll
    for (int r=0;r<4;r++){
      int m = m0 + wm + i*16 + quad*4 + r;
      #pragma unroll
      for (int j=0;j<4;j++){
        int n = wn + j*16 + mr;
        float lv = acc1[i][j][r] + bl[n];
        float gv = acc2[i][j][r] + bg[n];
        Out[(i64)m*128 + n] = lv * (1.f/(1.f + __expf(-gv)));
      }
    }
  }
}

// ---------------- generic batched GEMM (fp32, 64x64 tile) ----------------
template<bool TA, bool TB>
__global__ __launch_bounds__(256) void gemm_k(
    const float* __restrict__ A, int lda, i64 sA,
    const float* __restrict__ B, int ldb, i64 sB,
    float* __restrict__ C, int ldc, i64 sC,
    int M, int N, int K,
    const float* __restrict__ bias, float scale, int act,
    const float* __restrict__ rowmul, int combine)
{
  A += (i64)blockIdx.z * sA;
  B += (i64)blockIdx.z * sB;
  C += (i64)blockIdx.z * sC;
  int m0 = blockIdx.x * 64, n0 = blockIdx.y * 64;
  int tid = threadIdx.x, tx = tid & 15, ty = tid >> 4;
  __shared__ float As[16][68], Bs[16][68];
  float acc[4][4] = {};
  for (int k0 = 0; k0 < K; k0 += 16){
    if (TA){
      for (int l = tid; l < 1024; l += 256){
        int kk = l >> 6, mi = l & 63; int m = m0 + mi;
        As[kk][mi] = (m < M) ? A[(i64)(k0+kk)*lda + m] : 0.f;
      }
    } else {
      for (int l = tid; l < 1024; l += 256){
        int mi = l >> 4, kk = l & 15; int m = m0 + mi;
        As[kk][mi] = (m < M) ? A[(i64)m*lda + k0 + kk] : 0.f;
      }
    }
    if (TB){
      for (int l = tid; l < 1024; l += 256){
        int ni = l >> 4, kk = l & 15; int n = n0 + ni;
        Bs[kk][ni] = (n < N) ? B[(i64)n*ldb + k0 + kk] : 0.f;
      }
    } else {
      for (int l = tid; l < 1024; l += 256){
        int kk = l >> 6, ni = l & 63; int n = n0 + ni;
        Bs[kk][ni] = (n < N) ? B[(i64)(k0+kk)*ldb + n] : 0.f;
      }
    }
    __syncthreads();
    #pragma unroll
    for (int kk = 0; kk < 16; ++kk){
      float4 av4 = *(const float4*)&As[kk][ty*4];
      float4 bv4 = *(const float4*)&Bs[kk][tx*4];
      float av[4] = {av4.x, av4.y, av4.z, av4.w};
      float bv[4] = {bv4.x, bv4.y, bv4.z, bv4.w};
      #pragma unroll
      for (int i=0;i<4;i++)
        #pragma unroll
        for (int j=0;j<4;j++) acc[i][j] = fmaf(av[i], bv[j], acc[i][j]);
    }
    __syncthreads();
  }
  #pragma unroll
  for (int i=0;i<4;i++){
    int m = m0 + ty*4 + i;
    if (m >= M) continue;
    float rm = rowmul ? rowmul[m] : 1.f;
    #pragma unroll
    for (int j=0;j<4;j++){
      int n = n0 + tx*4 + j;
      if (n >= N) continue;
      float v = acc[i][j] * scale;
      if (bias) v += bias[n];
      if (act == 1) v = fmaxf(v, 0.f);
      else if (act == 2) v = 1.f/(1.f + expf(-v));
      v *= rm;
      i64 idx = (i64)m*ldc + n;
      if (combine == 0) C[idx] = v;
      else if (combine == 1) C[idx] += v;
      else C[idx] *= v;
    }
  }
}

// ---------------- thin GEMM (small M): split-K two-phase ----------------
__global__ __launch_bounds__(256) void gemm_part_k(
    const float* __restrict__ A, int lda,
    const float* __restrict__ B, int ldb,
    float* __restrict__ Cp, int M, int N, int K, int chunk)
{
  int m0 = blockIdx.x*16, n0 = blockIdx.y*64, z = blockIdx.z;
  int kb = z*chunk, ke = min(K, kb+chunk);
  int tid = threadIdx.x;
  int mi = tid >> 4, ni4 = (tid & 15)*4;
  __shared__ float As[16][17], Bs[16][68];
  float acc[4] = {0.f,0.f,0.f,0.f};
  for (int k0 = kb; k0 < ke; k0 += 16){
    { int r = tid>>4, c = tid&15; int m = m0+r;
      As[c][r] = (m < M) ? A[(i64)m*lda + k0 + c] : 0.f; }
    for (int l = tid; l < 1024; l += 256){
      int kk = l>>6, nn = l&63; int n = n0+nn;
      Bs[kk][nn] = (n < N) ? B[(i64)(k0+kk)*ldb + n] : 0.f;
    }
    __syncthreads();
    #pragma unroll
    for (int kk=0;kk<16;kk++){
      float a = As[kk][mi];
      float4 b = *(const float4*)&Bs[kk][ni4];
      acc[0]=fmaf(a,b.x,acc[0]); acc[1]=fmaf(a,b.y,acc[1]);
      acc[2]=fmaf(a,b.z,acc[2]); acc[3]=fmaf(a,b.w,acc[3]);
    }
    __syncthreads();
  }
  int m = m0+mi, n = n0+ni4;
  if (m < M && n < N) *(float4*)&Cp[((i64)z*M + m)*N + n] = *(float4*)acc;
}

__global__ __launch_bounds__(256) void gemm_reduce_k(
    const float* __restrict__ Cp, float* __restrict__ C, int ldc,
    int M, int N, int S,
    const float* __restrict__ bias, float scale, int act,
    const float* __restrict__ rowmul, int combine)
{
  i64 idx = (i64)blockIdx.x*256 + threadIdx.x;
  if (idx >= (i64)M*N) return;
  int m = (int)(idx / N), n = (int)(idx % N);
  float s = 0.f;
  for (int z=0; z<S; z++) s += Cp[(i64)z*M*N + idx];
  float v = s*scale;
  if (bias) v += bias[n];
  if (act == 1) v = fmaxf(v, 0.f);
  else if (act == 2) v = 1.f/(1.f + expf(-v));
  if (rowmul) v *= rowmul[m];
  i64 o = (i64)m*ldc + n;
  if (combine == 0) C[o] = v;
  else if (combine == 1) C[o] += v;
  else C[o] *= v;
}

// ---------------- OPM ----------------
__global__ __launch_bounds__(128) void opm_wd_k(const float* __restrict__ right, const float* __restrict__ W,
                                                float* __restrict__ Wd){
  int d = blockIdx.x, c = blockIdx.y, f = threadIdx.x;
  float acc = 0.f;
  #pragma unroll
  for (int e=0;e<32;e++) acc = fmaf(right[d*32+e], W[((i64)c*32+e)*128 + f], acc);
  Wd[((i64)d*32+c)*128 + f] = acc;
}

// pa[d,b,f] = pair_act[d,b,f] + (sum_c left[b,c]*Wd[d,c,f] + ob[f]) / (1e-3 + sm[d]*sm[b])
__global__ __launch_bounds__(128) void opm_final_k(const float* __restrict__ left, const float* __restrict__ Wd,
                                                   const float* __restrict__ ob, const float* __restrict__ sm,
                                                   const float* __restrict__ pair_act, float* __restrict__ pa){
  int d = blockIdx.x, b0 = blockIdx.y*16, f = threadIdx.x;
  __shared__ float wd_s[32][128];
  __shared__ float l_s[16][32];
  for (int c=0;c<32;c++) wd_s[c][f] = Wd[((i64)d*32+c)*128 + f];
  for (int l = f; l < 512; l += 128){ int bi=l>>5, c=l&31; l_s[bi][c] = left[(b0+bi)*32 + c]; }
  __syncthreads();
  float md = sm[d], obf = ob[f];
  for (int bi=0;bi<16;bi++){
    float acc = 0.f;
    #pragma unroll
    for (int c=0;c<32;c++) acc = fmaf(l_s[bi][c], wd_s[c][f], acc);
    int b = b0+bi;
    i64 idx = ((i64)d*256 + b)*128 + f;
    pa[idx] = pair_act[idx] + (acc + obf) / (1e-3f + md*sm[b]);
  }
}

// ---------------- row attention core ----------------
__global__ __launch_bounds__(256) void ra_attn_k(const float* __restrict__ q, const float* __restrict__ k,
                                                 const float* __restrict__ v, const float* __restrict__ nb,
                                                 const float* __restrict__ sm, float* __restrict__ wa){
  int qi = blockIdx.x, h = blockIdx.y, tid = threadIdx.x;
  __shared__ float qv[48];
  __shared__ float p[256];
  __shared__ float red[256];
  if (tid < 48) qv[tid] = q[(i64)qi*384 + h*48 + tid];
  __syncthreads();
  float acc = 0.f;
  const float* kr = k + (i64)tid*384 + h*48;
  #pragma unroll
  for (int c=0;c<48;c++) acc = fmaf(qv[c], kr[c], acc);
  acc += 1e9f*(sm[tid]-1.f) + nb[((i64)qi*256 + tid)*8 + h];
  red[tid] = acc; __syncthreads();
  for (int off=128;off>0;off>>=1){ if (tid<off) red[tid] = fmaxf(red[tid], red[tid+off]); __syncthreads(); }
  float mx = red[0]; __syncthreads();
  float e = expf(acc - mx);
  red[tid] = e; __syncthreads();
  for (int off=128;off>0;off>>=1){ if (tid<off) red[tid] += red[tid+off]; __syncthreads(); }
  p[tid] = e / red[0];
  __syncthreads();
  if (tid < 48){
    float a = 0.f;
    for (int kk=0;kk<256;kk++) a = fmaf(p[kk], v[(i64)kk*384 + h*48 + tid], a);
    wa[(i64)qi*384 + h*48 + tid] = a;
  }
}

// ---------------- triangle attention core v4: 1 q-row/thread, 256 thr (4 waves), 8-row K/V tiles ----
// Proven config (R7): VGPR 64, LDS 2048, occupancy ~37%, 181 µs. Do NOT add live state across the
// inner loop (v3 register prefetch spilled: VGPR 256 + 5.4 GB scratch traffic) and do NOT enlarge
// the tile (v5 16-row: LDS 4096/VGPR 68 -> occupancy 24%, 202 µs).
__global__ __launch_bounds__(256) void ta_attn_k(
    const float* __restrict__ q, const float* __restrict__ k, const float* __restrict__ v,
    const float* __restrict__ nbT, const float* __restrict__ mask, int maskT,
    float* __restrict__ wa)
{
  int b = blockIdx.x, h = blockIdx.y, tid = threadIdx.x;
  const i64 headoff = ((i64)b*256)*128 + h*32;
  const float* qp = q + headoff;
  const float* kp = k + headoff;
  const float* vp = v + headoff;
  const float* nbh = nbT + (i64)h*65536;

  float Q[32];
  #pragma unroll
  for (int cc = 0; cc < 32; cc += 4){
    float4 a = *(const float4*)(qp + (i64)tid*128 + cc);
    Q[cc]=a.x; Q[cc+1]=a.y; Q[cc+2]=a.z; Q[cc+3]=a.w;
  }
  float acc[32];
  #pragma unroll
  for (int c = 0; c < 32; c++) acc[c]=0.f;
  float mx=-1e30f, lsum=0.f;

  __shared__ float Ks[8][32];
  __shared__ float Vs[8][32];
  int r = tid >> 5, c = tid & 31;

  for (int kc = 0; kc < 256; kc += 8){
    __syncthreads();
    Ks[r][c] = kp[(i64)(kc+r)*128 + c];
    Vs[r][c] = vp[(i64)(kc+r)*128 + c];
    __syncthreads();
    float s[8];
    #pragma unroll
    for (int j = 0; j < 8; j++){
      float d = 0.f;
      #pragma unroll
      for (int cc = 0; cc < 32; cc += 4){
        float4 kv = *(const float4*)&Ks[j][cc];
        d = fmaf(Q[cc],kv.x,d); d = fmaf(Q[cc+1],kv.y,d);
        d = fmaf(Q[cc+2],kv.z,d); d = fmaf(Q[cc+3],kv.w,d);
      }
      int kk = kc + j;
      float mv = maskT ? mask[(i64)kk*256 + b] : mask[(i64)b*256 + kk];
      s[j] = d + 1e9f*(mv - 1.f) + nbh[(i64)kk*256 + tid];
    }
    float nm = mx;
    #pragma unroll
    for (int j=0;j<8;j++) nm = fmaxf(nm, s[j]);
    float alpha = __expf(mx-nm);
    mx = nm; lsum *= alpha;
    #pragma unroll
    for (int cc=0;cc<32;cc++) acc[cc] *= alpha;
    #pragma unroll
    for (int j=0;j<8;j++){
      float p = __expf(s[j]-mx);
      lsum += p;
      #pragma unroll
      for (int cc=0; cc<32; cc+=4){
        float4 vv = *(const float4*)&Vs[j][cc];
        acc[cc]  += p*vv.x; acc[cc+1]+= p*vv.y; acc[cc+2]+= p*vv.z; acc[cc+3]+= p*vv.w;
      }
    }
  }
  float inv = 1.f/lsum;
  float* w0 = wa + headoff + (i64)tid*128;
  #pragma unroll
  for (int cc=0; cc<32; cc+=4)
    *(float4*)(w0+cc) = make_float4(acc[cc]*inv, acc[cc+1]*inv, acc[cc+2]*inv, acc[cc+3]*inv);
}

// ---------------- host dispatch ----------------
static void gemm(hipStream_t st, bool TA, bool TB,
                 const float* A, int lda, i64 sA,
                 const float* B, int ldb, i64 sB,
                 float* C, int ldc, i64 sC,
                 int M, int N, int K, int batch,
                 const float* bias, float scale, int act,
                 const float* rowmul, int combine)
{
  dim3 g((M+63)/64, (N+63)/64, batch), bl(256);
  if (!TA && !TB)      gemm_k<false,false><<<g,bl,0,st>>>(A,lda,sA,B,ldb,sB,C,ldc,sC,M,N,K,bias,scale,act,rowmul,combine);
  else if (!TA &&  TB) gemm_k<false,true ><<<g,bl,0,st>>>(A,lda,sA,B,ldb,sB,C,ldc,sC,M,N,K,bias,scale,act,rowmul,combine);
  else                 gemm_k<true ,false><<<g,bl,0,st>>>(A,lda,sA,B,ldb,sB,C,ldc,sC,M,N,K,bias,scale,act,rowmul,combine);
}

static void mgemm(hipStream_t st, bool TA, bool TB,
                  const float* A, int lda, i64 sA,
                  const float* B, int ldb, i64 sB,
                  float* C, int ldc, i64 sC,
                  int M, int N, int K, int batch,
                  const float* bias, float scale, int act,
                  const float* rowmul, int combine, const float* aux = nullptr)
{
  dim3 g(M/128, N/128, batch), bl(256);
  if (!TA && !TB)      mgemm_k<false,false><<<g,bl,0,st>>>(A,lda,sA,B,ldb,sB,C,ldc,sC,M,N,K,bias,scale,act,rowmul,combine,aux);
  else if (!TA &&  TB) mgemm_k<false,true ><<<g,bl,0,st>>>(A,lda,sA,B,ldb,sB,C,ldc,sC,M,N,K,bias,scale,act,rowmul,combine,aux);
  else                 mgemm_k<true ,false><<<g,bl,0,st>>>(A,lda,sA,B,ldb,sB,C,ldc,sC,M,N,K,bias,scale,act,rowmul,combine,aux);
}

static void gemm_thin(hipStream_t st,
                      const float* A, int lda, const float* B, int ldb,
                      float* C, int ldc, int M, int N, int K,
                      const float* bias, float scale, int act,
                      const float* rowmul, int combine, float* part)
{
  const int S = 8;
  int chunk = ((K/S + 15)/16)*16; if (chunk < 16) chunk = 16;
  dim3 g((M+15)/16, (N+63)/64, S);
  gemm_part_k<<<g,256,0,st>>>(A,lda,B,ldb,part,M,N,K,chunk);
  i64 t = (i64)M*N;
  gemm_reduce_k<<<(int)((t+255)/256),256,0,st>>>(part,C,ldc,M,N,S,bias,scale,act,rowmul,combine);
}

extern "C" void kernel_launch(void* const* d_in, const int* in_sizes, int n_in,
                              void* d_out, int out_size, void* d_ws, size_t ws_size,
                              hipStream_t stream)
{
  const float* IN[64];
  for (int i=0;i<n_in && i<64;i++) IN[i] = (const float*)d_in[i];

  const float* single_act = IN[0];
  const float* pair_act   = IN[1];
  const float* sm         = IN[2];
  const float* pm         = IN[3];
  const float* opm_ln     = IN[4];
  const float* opm_lr_w   = IN[5];
  const float* opm_lr_b   = IN[6];
  const float* opm_out_w  = IN[7];
  const float* opm_out_b  = IN[8];
  const float* ra_ln      = IN[9];
  const float* ra_pair_ln = IN[10];
  const float* ra_feat_w  = IN[11];
  const float* ra_qkv_w   = IN[12];
  const float* ra_gate_w  = IN[13];
  const float* ra_gate_b  = IN[14];
  const float* ra_o_w     = IN[15];
  const float* ra_o_b     = IN[16];
  const float* st_ln      = IN[17];
  const float* st_w1      = IN[18];
  const float* st_b1      = IN[19];
  const float* st_w2      = IN[20];
  const float* st_b2      = IN[21];
  const float* pt_ln      = IN[56];
  const float* pt_w1      = IN[57];
  const float* pt_b1      = IN[58];
  const float* pt_w2      = IN[59];
  const float* pt_b2      = IN[60];

  float* sa = (float*)d_out;           // [256,384]
  float* pa = (float*)d_out + 98304;   // [256,256,128]

  float* W  = (float*)d_ws;
  float* B0 = W;
  float* B1 = W + 8388608L;
  float* B2 = W + 16777216L;
  float* B3 = W + 25165824L;
  float* SMA = W + 33554432L;
  float* xs   = SMA;
  float* qb   = SMA +  98304;
  float* kb   = SMA + 196608;
  float* vb   = SMA + 294912;
  float* wab  = SMA + 393216;
  float* hst  = SMA + 491520;   // 393216
  float* nbra = SMA + 884736;   // 524288 (reused as nbT in tri-attn phase)
  float* lbuf = SMA + 1409024;  // 8192
  float* rbuf = SMA + 1417216;  // 8192
  float* Wd   = SMA + 1425408;  // 1048576
  float* nbt  = SMA + 2473984;  // 262144

  // init sa with residual base (pa is initialized by opm_final_k's fused write)
  copy_k<<<384, 256, 0, stream>>>(sa, single_act, 98304L);

  // ---- 1) OPM -> pair residual (writes pa = pair_act + update) ----
  ln_k<<<256,128,0,stream>>>(single_act, xs, opm_ln, 384);
  gemm_thin(stream, xs,384, opm_lr_w,32,       lbuf,32, 256,32,384, opm_lr_b,    1.f,0, sm,0, B1);
  gemm_thin(stream, xs,384, opm_lr_w+12288,32, rbuf,32, 256,32,384, opm_lr_b+32, 1.f,0, sm,0, B1);
  opm_wd_k<<<dim3(256,32),128,0,stream>>>(rbuf, opm_out_w, Wd);
  opm_final_k<<<dim3(256,16),128,0,stream>>>(lbuf, Wd, opm_out_b, sm, pair_act, pa);

  // ---- 2) row attention with pair bias ----
  ln_k<<<256,128,0,stream>>>(sa, xs, ra_ln, 384);
  ln128_k<<<16384,256,0,stream>>>(pa, B0, ra_pair_ln, 0);
  gemm(stream,false,false, B0,128,0, ra_feat_w,8,0, nbra,8,0, 65536,8,128,1, nullptr,1.f,0,nullptr,0);
  const float qs_ra = 0.14433756729740643f; // 1/sqrt(48)
  gemm_thin(stream, xs,384, ra_qkv_w,384,        qb,384, 256,384,384, nullptr,qs_ra,0,nullptr,0, B1);
  gemm_thin(stream, xs,384, ra_qkv_w+147456,384, kb,384, 256,384,384, nullptr,1.f,0,nullptr,0, B1);
  gemm_thin(stream, xs,384, ra_qkv_w+294912,384, vb,384, 256,384,384, nullptr,1.f,0,nullptr,0, B1);
  ra_attn_k<<<dim3(256,8),256,0,stream>>>(qb, kb, vb, nbra, sm, wab);
  gemm_thin(stream, xs,384,  ra_gate_w,384, wab,384, 256,384,384, ra_gate_b,1.f,2,nullptr,2, B1);
  gemm_thin(stream, wab,384, ra_o_w,384,    sa,384,  256,384,384, ra_o_b,   1.f,0,nullptr,1, B1);

  // ---- 3) single transition ----
  ln_k<<<256,128,0,stream>>>(sa, xs, st_ln, 384);
  gemm_thin(stream, xs,384,   st_w1,1536, hst,1536, 256,1536,384, st_b1,1.f,1,nullptr,0, B1);
  gemm_thin(stream, hst,1536, st_w2,384,  sa,384,   256,384,1536, st_b2,1.f,0,nullptr,1, B1);

  // ---- 4/5) triangle multiplications ----
  auto tri_mult = [&](int base, bool outgoing){
    const float* ln_w = IN[base+0];
    const float* lr_w = IN[base+1];
    const float* lr_b = IN[base+2];
    const float* gw   = IN[base+3];
    const float* gb   = IN[base+4];
    const float* cln  = IN[base+5];
    const float* ow   = IN[base+6];
    const float* ob   = IN[base+7];
    const float* ogw  = IN[base+8];
    const float* ogb  = IN[base+9];
    ln128_k<<<16384,256,0,stream>>>(pa, B0, ln_w, 0);
    // left = mask * (X@Wl+bl) * sigmoid(X@Wg+bg): fused dual-MFMA, then transpose+mask -> B1 (ch-major)
    mlrgate_k<<<512,256,0,stream>>>(B0, lr_w, lr_b, gw, gb, B3);
    tr_mask_k<<<dim3(2048,4),256,0,stream>>>(B3, pm, B1);
    // right -> B2 (ch-major)
    mlrgate_k<<<512,256,0,stream>>>(B0, lr_w+16384, lr_b+128, gw+16384, gb+128, B3);
    tr_mask_k<<<dim3(2048,4),256,0,stream>>>(B3, pm, B2);
    if (outgoing) // out[i,j,c] = sum_k L_c[i,k] * R_c[j,k]
      mgemm(stream,false,true, B1,256,65536, B2,256,65536, B3,256,65536, 256,256,256,128, nullptr,1.f,0,nullptr,0);
    else          // out[i,j,c] = sum_k R_c[k,i] * L_c[k,j]
      mgemm(stream,true,false, B2,256,65536, B1,256,65536, B3,256,65536, 256,256,256,128, nullptr,1.f,0,nullptr,0);
    chw2hwc_k<<<dim3(2048,4),256,0,stream>>>(B3, B1);
    ln128_k<<<16384,256,0,stream>>>(B1, B3, cln, 0);
    mgemm(stream,false,false, B3,128,0, ow,128,0,  B1,128,0, 65536,128,128,1, ob,  1.f,0,nullptr,0);
    // fused: pa += B1 * sigmoid(B0@ogw + ogb)
    mgemm(stream,false,false, B0,128,0, ogw,128,0, pa,128,0, 65536,128,128,1, ogb, 1.f,2,nullptr,3, B1);
  };
  tri_mult(22, true);   // tmo
  tri_mult(32, false);  // tmi

  // ---- 6/7) triangle attentions ----
  auto tri_attn = [&](int base, bool percol){
    const float* ln_w   = IN[base+0];
    const float* feat_w = IN[base+1];
    const float* qkv_w  = IN[base+2];
    const float* gw     = IN[base+3];
    const float* gb     = IN[base+4];
    const float* ow     = IN[base+5];
    const float* ob     = IN[base+6];
    // LN with fused pair-transpose read for per-column attention
    ln128_k<<<16384,256,0,stream>>>(pa, B0, ln_w, percol?1:0);
    gemm(stream,false,false, B0,128,0, feat_w,4,0, nbt,4,0, 65536,4,128,1, nullptr,1.f,0,nullptr,0);
    nbT_k<<<256,256,0,stream>>>(nbt, nbra);  // nbT[h][k][q]
    const float qs = 0.17677669529663687f; // 1/sqrt(32)
    mgemm(stream,false,false, B0,128,0, qkv_w,128,0,       B1,128,0, 65536,128,128,1, nullptr,qs, 0,nullptr,0);
    mgemm(stream,false,false, B0,128,0, qkv_w+16384,128,0, B2,128,0, 65536,128,128,1, nullptr,1.f,0,nullptr,0);
    mgemm(stream,false,false, B0,128,0, qkv_w+32768,128,0, B3,128,0, 65536,128,128,1, nullptr,1.f,0,nullptr,0);
    ta_attn_k<<<dim3(256,4),256,0,stream>>>(B1, B2, B3, nbra, pm, percol?1:0, B1);
    mgemm(stream,false,false, B0,128,0, gw,128,0, B1,128,0, 65536,128,128,1, gb,1.f,2,nullptr,2); // wa *= sigmoid(gate)
    // out-projection fused with residual add (4 = transpose-pair write for per-column)
    mgemm(stream,false,false, B1,128,0, ow,128,0, pa,128,0, 65536,128,128,1, ob,1.f,0,nullptr, percol?4:1);
  };
  tri_attn(42, false);  // tas (per-row)
  tri_attn(49, true);   // tae (per-column)

  // ---- 8) pair transition ----
  ln128_k<<<16384,256,0,stream>>>(pa, B0, pt_ln, 0);
  for (int half = 0; half < 2; half++){
    const float* xh = B0 + (i64)half*4194304;
    float* ph = pa + (i64)half*4194304;
    mgemm(stream,false,false, xh,128,0, pt_w1,512,0, B1,512,0, 32768,512,128,1, pt_b1,1.f,1,nullptr,0);
    mgemm(stream,false,false, B1,512,0, pt_w2,128,0, ph,128,0, 32768,128,512,1, pt_b2,1.f,0,nullptr,1);
  }
}